// Round 1
// 752.012 us; speedup vs baseline: 1.1594x; 1.1594x over previous
//
#include <hip/hip_runtime.h>
#include <math.h>

#ifndef M_PI
#define M_PI 3.14159265358979323846
#endif

#define NGRID 513
#define NCELL 512
#define NINT  511
#define NB    4

constexpr int N2G = NGRID * NGRID;   // 263169
constexpr int NI2 = NINT * NINT;     // 261121
constexpr int NTT = NGRID * NINT;    // 262143

typedef unsigned short ushort;
typedef unsigned int uint32;
typedef __attribute__((ext_vector_type(8))) short short8;
typedef __attribute__((ext_vector_type(8))) unsigned short ushort8;
typedef __attribute__((ext_vector_type(4))) float f32x4;

// ---------------------------------------------------------------------------
// bf16 split helpers (RNE)
// ---------------------------------------------------------------------------
__device__ __forceinline__ ushort f2bf(float x) {
    unsigned u = __float_as_uint(x);
    unsigned r = u + 0x7FFFu + ((u >> 16) & 1u);
    return (ushort)(r >> 16);
}
__device__ __forceinline__ float bf2f(ushort h) {
    return __uint_as_float(((unsigned)h) << 16);
}

// ---------------------------------------------------------------------------
// FEM Darcy operator at interior node (i,j), i,j in 1..511
// ---------------------------------------------------------------------------
__device__ __forceinline__ float darcyA(const float* __restrict__ x,
                                        const float* __restrict__ a,
                                        int i, int j) {
    const float c23 = 2.0f / 3.0f, c16 = 1.0f / 6.0f, c13 = 1.0f / 3.0f;
    float a00 = a[(i - 1) * NCELL + (j - 1)];
    float a01 = a[(i - 1) * NCELL + j];
    float a10 = a[i * NCELL + (j - 1)];
    float a11 = a[i * NCELL + j];
    const float* xm = x + (i - 1) * NGRID;
    const float* xc = x + i * NGRID;
    const float* xp = x + (i + 1) * NGRID;
    return c23 * (a00 + a01 + a10 + a11) * xc[j]
         - c16 * ((a00 + a01) * xm[j] + (a10 + a11) * xp[j]
                + (a00 + a10) * xc[j - 1] + (a01 + a11) * xc[j + 1])
         - c13 * (a00 * xm[j - 1] + a01 * xm[j + 1]
                + a10 * xp[j - 1] + a11 * xp[j + 1]);
}

__global__ void k_stencil(const float* __restrict__ xin,
                          const float* __restrict__ a,
                          const float* __restrict__ f,
                          const float* __restrict__ dinv,
                          float* __restrict__ out, int mode) {
    int b = blockIdx.z;
    int j = blockIdx.x * 16 + threadIdx.x;
    int i = blockIdx.y * 16 + threadIdx.y;
    if (i >= NGRID || j >= NGRID) return;
    const float* xb = xin + (long long)b * N2G;
    const float* ab = a + (long long)b * NCELL * NCELL;
    long long idx = (long long)b * N2G + (long long)i * NGRID + j;
    bool interior = (i >= 1 && i <= NINT && j >= 1 && j <= NINT);
    if (!interior) {
        out[idx] = (mode == 0) ? f[idx] : 0.0f;
        return;
    }
    float Ax = darcyA(xb, ab, i, j);
    if (mode == 0) {
        out[idx] = f[idx] - Ax;
    } else {
        out[idx] = Ax;
    }
}

// ---------------------------------------------------------------------------
// 5 fused weighted-Jacobi sweeps per launch (halo 5, LDS ping-pong stages).
// ---------------------------------------------------------------------------
__global__ void k_jacobi5(const float* __restrict__ xin,
                          const float* __restrict__ a,
                          const float* __restrict__ f,
                          const float* __restrict__ dinv,
                          float* __restrict__ out) {
    __shared__ float sx[26][26];
    __shared__ float sa[25][26];
    __shared__ float sf[24][24];
    __shared__ float sd[24][24];
    __shared__ float sp[2][24][26];
    const float c23 = 2.0f / 3.0f, c16 = 1.0f / 6.0f, c13 = 1.0f / 3.0f;
    int b = blockIdx.z;
    const float* xb = xin + (long long)b * N2G;
    const float* ab = a + (long long)b * NCELL * NCELL;
    const float* fb = f + (long long)b * N2G;
    const float* db = dinv + (long long)b * NI2;
    int ox = blockIdx.x * 16, oy = blockIdx.y * 16;
    int tx = threadIdx.x, ty = threadIdx.y;
    int tid = ty * 16 + tx;

    for (int idx = tid; idx < 26 * 26; idx += 256) {
        int ly = idx / 26, lx = idx % 26;
        int gy = oy - 5 + ly, gx = ox - 5 + lx;
        bool in = (gy >= 0 && gy < NGRID && gx >= 0 && gx < NGRID);
        sx[ly][lx] = in ? xb[(long long)gy * NGRID + gx] : 0.0f;
    }
    for (int idx = tid; idx < 25 * 25; idx += 256) {
        int ly = idx / 25, lx = idx % 25;
        int gy = oy - 5 + ly, gx = ox - 5 + lx;
        bool in = (gy >= 0 && gy < NCELL && gx >= 0 && gx < NCELL);
        sa[ly][lx] = in ? ab[(long long)gy * NCELL + gx] : 0.0f;
    }
    for (int idx = tid; idx < 24 * 24; idx += 256) {
        int ly = idx / 24, lx = idx % 24;
        int gy = oy - 4 + ly, gx = ox - 4 + lx;
        bool ing = (gy >= 0 && gy < NGRID && gx >= 0 && gx < NGRID);
        bool itr = (gy >= 1 && gy <= NINT && gx >= 1 && gx <= NINT);
        sf[ly][lx] = ing ? fb[(long long)gy * NGRID + gx] : 0.0f;
        sd[ly][lx] = itr ? db[(long long)(gy - 1) * NINT + (gx - 1)] : 0.0f;
    }
    __syncthreads();

    for (int idx = tid; idx < 24 * 24; idx += 256) {
        int ly = idx / 24, lx = idx % 24;
        int gy = oy - 4 + ly, gx = ox - 4 + lx;
        float v = 0.0f;
        if (gy >= 0 && gy < NGRID && gx >= 0 && gx < NGRID) {
            float xc = sx[ly + 1][lx + 1];
            if (gy >= 1 && gy <= NINT && gx >= 1 && gx <= NINT) {
                float a00 = sa[ly][lx], a01 = sa[ly][lx + 1];
                float a10 = sa[ly + 1][lx], a11 = sa[ly + 1][lx + 1];
                float Ax = c23 * (a00 + a01 + a10 + a11) * xc
                    - c16 * ((a00 + a01) * sx[ly][lx + 1] + (a10 + a11) * sx[ly + 2][lx + 1]
                           + (a00 + a10) * sx[ly + 1][lx] + (a01 + a11) * sx[ly + 1][lx + 2])
                    - c13 * (a00 * sx[ly][lx] + a01 * sx[ly][lx + 2]
                           + a10 * sx[ly + 2][lx] + a11 * sx[ly + 2][lx + 2]);
                v = xc + 0.75f * sd[ly][lx] * (sf[ly][lx] - Ax);
            } else {
                v = xc;
            }
        }
        sp[0][ly][lx] = v;
    }
    __syncthreads();

    #pragma unroll 1
    for (int s = 2; s <= 4; ++s) {
        int sz = 24 - 2 * (s - 1);
        int cur = (s - 1) & 1, prv = s & 1;
        for (int idx = tid; idx < sz * sz; idx += 256) {
            int ly = idx / sz, lx = idx % sz;
            int gy = oy - (5 - s) + ly, gx = ox - (5 - s) + lx;
            float v = 0.0f;
            if (gy >= 0 && gy < NGRID && gx >= 0 && gx < NGRID) {
                float xc = sp[prv][ly + 1][lx + 1];
                if (gy >= 1 && gy <= NINT && gx >= 1 && gx <= NINT) {
                    int ar = ly + s - 1, ac = lx + s - 1;
                    float a00 = sa[ar][ac], a01 = sa[ar][ac + 1];
                    float a10 = sa[ar + 1][ac], a11 = sa[ar + 1][ac + 1];
                    float Ax = c23 * (a00 + a01 + a10 + a11) * xc
                        - c16 * ((a00 + a01) * sp[prv][ly][lx + 1] + (a10 + a11) * sp[prv][ly + 2][lx + 1]
                               + (a00 + a10) * sp[prv][ly + 1][lx] + (a01 + a11) * sp[prv][ly + 1][lx + 2])
                        - c13 * (a00 * sp[prv][ly][lx] + a01 * sp[prv][ly][lx + 2]
                               + a10 * sp[prv][ly + 2][lx] + a11 * sp[prv][ly + 2][lx + 2]);
                    int fr = ly + s - 1, fc = lx + s - 1;
                    v = xc + 0.75f * sd[fr][fc] * (sf[fr][fc] - Ax);
                } else {
                    v = xc;
                }
            }
            sp[cur][ly][lx] = v;
        }
        __syncthreads();
    }

    {
        int gy = oy + ty, gx = ox + tx;
        if (gy < NGRID && gx < NGRID) {
            float v;
            float xc = sp[1][ty + 1][tx + 1];
            if (gy >= 1 && gy <= NINT && gx >= 1 && gx <= NINT) {
                int ar = ty + 4, ac = tx + 4;
                float a00 = sa[ar][ac], a01 = sa[ar][ac + 1];
                float a10 = sa[ar + 1][ac], a11 = sa[ar + 1][ac + 1];
                float Ax = c23 * (a00 + a01 + a10 + a11) * xc
                    - c16 * ((a00 + a01) * sp[1][ty][tx + 1] + (a10 + a11) * sp[1][ty + 2][tx + 1]
                           + (a00 + a10) * sp[1][ty + 1][tx] + (a01 + a11) * sp[1][ty + 1][tx + 2])
                    - c13 * (a00 * sp[1][ty][tx] + a01 * sp[1][ty][tx + 2]
                           + a10 * sp[1][ty + 2][tx] + a11 * sp[1][ty + 2][tx + 2]);
                v = xc + 0.75f * sd[ty + 4][tx + 4] * (sf[ty + 4][tx + 4] - Ax);
            } else {
                v = xc;
            }
            out[(long long)b * N2G + (long long)gy * NGRID + gx] = v;
        }
    }
}

__global__ void k_dinv(const float* __restrict__ a, float* __restrict__ dinv) {
    long long idx = (long long)blockIdx.x * blockDim.x + threadIdx.x;
    if (idx >= (long long)NB * NI2) return;
    int b = (int)(idx / NI2);
    int rem = (int)(idx % NI2);
    int p = rem / NINT, q = rem % NINT;
    const float* ab = a + (long long)b * NCELL * NCELL;
    float s = ab[p * NCELL + q] + ab[p * NCELL + q + 1]
            + ab[(p + 1) * NCELL + q] + ab[(p + 1) * NCELL + q + 1];
    dinv[idx] = 1.0f / ((2.0f / 3.0f) * s);
}

// ---------------------------------------------------------------------------
// Static bf16 matrix generation (hi/lo planes, K-padded, integer arg reduce)
// ---------------------------------------------------------------------------
__device__ __forceinline__ void wsplit(double v, ushort* Dh, ushort* Dl, int idx) {
    float vf = (float)v;
    ushort h = f2bf(vf);
    Dh[idx] = h;
    Dl[idx] = f2bf(vf - bf2f(h));
}

__global__ void k_genDSTA(ushort* __restrict__ Dh, ushort* __restrict__ Dl) {
    int idx = blockIdx.x * 256 + threadIdx.x;
    if (idx >= 513 * 512) return;
    int u = idx / 512, k = idx % 512;
    double v = 0.0;
    if (k < 511) {
        int t = ((u - 256) * (k + 1)) % 1024;
        if (t < 0) t += 1024;
        v = sin((M_PI / 512.0) * (double)t);
    }
    wsplit(v, Dh, Dl, idx);
}

__global__ void k_genDSTB(ushort* __restrict__ Dh, ushort* __restrict__ Dl) {
    int idx = blockIdx.x * 256 + threadIdx.x;
    if (idx >= 513 * 512) return;
    int v = idx / 512, k = idx % 512;
    double val = 0.0;
    if (k < 511) {
        int t = ((v - 256) * (k + 1)) % 1024;
        if (t < 0) t += 1024;
        val = sin((M_PI / 512.0) * (double)t) * (-1.0 / 262144.0);
    }
    wsplit(val, Dh, Dl, idx);
}

__global__ void k_genFA(ushort* __restrict__ Dh, ushort* __restrict__ Dl) {
    int idx = blockIdx.x * 256 + threadIdx.x;
    if (idx >= 511 * 1056) return;
    int y = idx / 1056, k = idx % 1056;
    double v = 0.0;
    if (k < 1026) {
        int m = (k < 513) ? k : (k - 513);
        long t = ((long)y * (m - 255)) % 1025;
        if (t < 0) t += 1025;
        double ang = (2.0 * M_PI / 1025.0) * (double)t;
        v = (k < 513) ? cos(ang) : -sin(ang);
    }
    wsplit(v, Dh, Dl, idx);
}

__global__ void k_genFB(ushort* __restrict__ Dh, ushort* __restrict__ Dl) {
    int idx = blockIdx.x * 256 + threadIdx.x;
    if (idx >= 1022 * 1056) return;
    int n = idx / 1056, k = idx % 1056;
    double v = 0.0;
    if (k < 1026) {
        int m = (k < 513) ? k : (k - 513);
        int y = (n < 511) ? n : (n - 511);
        long t = ((long)y * (m - 255)) % 1025;
        if (t < 0) t += 1025;
        double ang = (2.0 * M_PI / 1025.0) * (double)t;
        bool ktop = (k < 513), nleft = (n < 511);
        if (ktop && nleft)        v = cos(ang);
        else if (ktop && !nleft)  v = -sin(ang);
        else if (!ktop && nleft)  v = sin(ang);
        else                      v = cos(ang);
    }
    wsplit(v, Dh, Dl, idx);
}

// ---------------------------------------------------------------------------
// Dynamic fp32 -> bf16 hi/lo conversion (inputs to gemm1 / gemm3).
// ---------------------------------------------------------------------------
__global__ void k_cvtA(const float* __restrict__ s1, const float* __restrict__ s2,
                       long long bs1, long long bs2, int ld1, int ld2, int S,
                       int M, int K, int Kp,
                       ushort* __restrict__ Dh, ushort* __restrict__ Dl) {
    int b = blockIdx.y;
    int idx = blockIdx.x * 256 + threadIdx.x;
    if (idx >= M * Kp) return;
    int m = idx / Kp, k = idx % Kp;
    float v = 0.0f;
    if (k < K)
        v = (k < S) ? s1[b * bs1 + (long long)m * ld1 + k]
                    : s2[b * bs2 + (long long)m * ld2 + (k - S)];
    long long o = (long long)b * M * Kp + idx;
    ushort h = f2bf(v);
    Dh[o] = h;
    Dl[o] = f2bf(v - bf2f(h));
}

__global__ void k_cvtBt(const float* __restrict__ s1,
                        long long bs1, int ld1,
                        int N, int K, int Kp,
                        ushort* __restrict__ Dh, ushort* __restrict__ Dl) {
    int b = blockIdx.y;
    int idx = blockIdx.x * 256 + threadIdx.x;
    if (idx >= N * Kp) return;
    int n = idx / Kp, k = idx % Kp;
    float v = 0.0f;
    if (k < K)
        v = s1[b * bs1 + (long long)k * ld1 + n];
    long long o = (long long)b * N * Kp + idx;
    ushort h = f2bf(v);
    Dh[o] = h;
    Dl[o] = f2bf(v - bf2f(h));
}

// ---------------------------------------------------------------------------
// Fused split-K reduce + bf16 convert (GEMM->GEMM handoffs).
// ---------------------------------------------------------------------------
__global__ void k_redA(const float* __restrict__ P, int nsplit,
                       ushort* __restrict__ Dh, ushort* __restrict__ Dl) {
    int b = blockIdx.y;
    int idx = blockIdx.x * 256 + threadIdx.x;
    if (idx >= 513 * 512) return;
    int m = idx / 512, k = idx % 512;
    float v = 0.0f;
    if (k < 511) {
        long long base = (long long)m * 511 + k;
        #pragma unroll 4
        for (int s = 0; s < nsplit; ++s)
            v += P[((long long)b * nsplit + s) * NTT + base];
    }
    long long o = (long long)b * 513 * 512 + idx;
    ushort h = f2bf(v);
    Dh[o] = h;
    Dl[o] = f2bf(v - bf2f(h));
}

__global__ void k_redBt(const float* __restrict__ P, int nsplit,
                        ushort* __restrict__ Dh, ushort* __restrict__ Dl) {
    int b = blockIdx.y;
    int idx = blockIdx.x * 256 + threadIdx.x;
    if (idx >= 511 * 1056) return;
    int n = idx / 1056, k = idx % 1056;
    float v = 0.0f;
    if (k < 1026) {
        int row = (k < 513) ? n : (511 + n);
        int col = (k < 513) ? k : (k - 513);
        long long base = (long long)row * 513 + col;
        float acc = 0.0f;
        #pragma unroll 4
        for (int s = 0; s < nsplit; ++s)
            acc += P[((long long)b * nsplit + s) * (1022LL * 513) + base];
        v = (k < 513) ? acc : -acc;
    }
    long long o = (long long)b * 511 * 1056 + idx;
    ushort h = f2bf(v);
    Dh[o] = h;
    Dl[o] = f2bf(v - bf2f(h));
}

// ---------------------------------------------------------------------------
// MFMA real GEMM, 3-term split-bf16 (hh + hl + lh), 16x16x32 bf16 MFMA.
// ---------------------------------------------------------------------------
__global__ __launch_bounds__(256) void k_mgemm(
    const ushort* __restrict__ Ah, const ushort* __restrict__ Al, long long bsA,
    const ushort* __restrict__ Bh, const ushort* __restrict__ Bl, long long bsB,
    float* __restrict__ C, long long bsC,
    int M, int N, int Kp, int nsplit) {
    __shared__ ushort sAh[128 * 40];
    __shared__ ushort sAl[128 * 40];
    __shared__ ushort sBh[128 * 40];
    __shared__ ushort sBl[128 * 40];

    int bz = blockIdx.z, b = bz / nsplit, ks = bz % nsplit;
    int kchunk = (((Kp + nsplit - 1) / nsplit) + 31) & ~31;
    int kbeg = ks * kchunk;
    int kend = min(Kp, kbeg + kchunk);

    Ah += b * bsA; Al += b * bsA;
    Bh += b * bsB; Bl += b * bsB;
    C += ((long long)b * nsplit + ks) * bsC;

    int bm = blockIdx.y * 128, bn = blockIdx.x * 128;
    int tid = threadIdx.x;
    int wave = tid >> 6, lane = tid & 63;
    int wm = (wave >> 1) * 64, wn = (wave & 1) * 64;
    int quad = lane >> 4, l16 = lane & 15;

    f32x4 zf = {0.f, 0.f, 0.f, 0.f};
    f32x4 acc[4][4];
    #pragma unroll
    for (int i = 0; i < 4; ++i)
        #pragma unroll
        for (int j = 0; j < 4; ++j) acc[i][j] = zf;

    int srow = tid >> 2;
    int sk8 = (tid & 3) * 8;

    for (int kt = kbeg; kt < kend; kt += 32) {
        #pragma unroll
        for (int h = 0; h < 2; ++h) {
            int row = srow + 64 * h;
            ushort8 vh = {0, 0, 0, 0, 0, 0, 0, 0};
            ushort8 vl = {0, 0, 0, 0, 0, 0, 0, 0};
            int gm = bm + row;
            if (gm < M) {
                vh = *(const ushort8*)(Ah + (long long)gm * Kp + kt + sk8);
                vl = *(const ushort8*)(Al + (long long)gm * Kp + kt + sk8);
            }
            *(ushort8*)(sAh + row * 40 + sk8) = vh;
            *(ushort8*)(sAl + row * 40 + sk8) = vl;
            ushort8 wh = {0, 0, 0, 0, 0, 0, 0, 0};
            ushort8 wl = {0, 0, 0, 0, 0, 0, 0, 0};
            int gn = bn + row;
            if (gn < N) {
                wh = *(const ushort8*)(Bh + (long long)gn * Kp + kt + sk8);
                wl = *(const ushort8*)(Bl + (long long)gn * Kp + kt + sk8);
            }
            *(ushort8*)(sBh + row * 40 + sk8) = wh;
            *(ushort8*)(sBl + row * 40 + sk8) = wl;
        }
        __syncthreads();

        short8 afh[4], afl[4], bfh[4], bfl[4];
        #pragma unroll
        for (int t = 0; t < 4; ++t) {
            int ar = wm + t * 16 + l16;
            afh[t] = *(const short8*)(sAh + ar * 40 + quad * 8);
            afl[t] = *(const short8*)(sAl + ar * 40 + quad * 8);
            int br = wn + t * 16 + l16;
            bfh[t] = *(const short8*)(sBh + br * 40 + quad * 8);
            bfl[t] = *(const short8*)(sBl + br * 40 + quad * 8);
        }
        #pragma unroll
        for (int mt = 0; mt < 4; ++mt)
            #pragma unroll
            for (int nt = 0; nt < 4; ++nt) {
                acc[mt][nt] = __builtin_amdgcn_mfma_f32_16x16x32_bf16(
                    afh[mt], bfh[nt], acc[mt][nt], 0, 0, 0);
                acc[mt][nt] = __builtin_amdgcn_mfma_f32_16x16x32_bf16(
                    afh[mt], bfl[nt], acc[mt][nt], 0, 0, 0);
                acc[mt][nt] = __builtin_amdgcn_mfma_f32_16x16x32_bf16(
                    afl[mt], bfh[nt], acc[mt][nt], 0, 0, 0);
            }
        __syncthreads();
    }

    #pragma unroll
    for (int mt = 0; mt < 4; ++mt) {
        #pragma unroll
        for (int r = 0; r < 4; ++r) {
            int gm = bm + wm + mt * 16 + quad * 4 + r;
            if (gm >= M) continue;
            long long rowoff = (long long)gm * N;
            #pragma unroll
            for (int nt = 0; nt < 4; ++nt) {
                int gn = bn + wn + nt * 16 + l16;
                if (gn < N) C[rowoff + gn] = acc[mt][nt][r];
            }
        }
    }
}

// ---------------------------------------------------------------------------
// Sum nsplit dense [M x N] partials -> strided fp32 output (row stride ldo).
// ---------------------------------------------------------------------------
__global__ void k_reduce(const float* __restrict__ Pr,
                         float* __restrict__ outR,
                         int MN, int N, int ldo, long long bsOut, int nsplit) {
    int b = blockIdx.y;
    for (int idx = blockIdx.x * 256 + threadIdx.x; idx < MN;
         idx += gridDim.x * 256) {
        float sr = 0.0f;
        #pragma unroll 4
        for (int s = 0; s < nsplit; ++s)
            sr += Pr[((long long)b * nsplit + s) * MN + idx];
        int m = idx / N, n = idx - m * N;
        outR[(long long)b * bsOut + (long long)m * ldo + n] = sr;
    }
}

// ---------------------------------------------------------------------------
// R17: composed conv-chain. The three complex 3x3 convs of each chain
// (fwd: w1,w2,w3 / adj: conjT(w3),conjT(w2),conjT(w1)) are linear with no
// pointwise op between them, and channel dims are internal (1->4->4->1),
// so each chain == ONE complex 7x7 conv (per batch). The zero-pad of each
// stage makes the composition inexact only on a ring of width 2 at the
// border, which k_ring7 recomputes with the exact sequential semantics.
// ---------------------------------------------------------------------------
__device__ __forceinline__ float2 cmul(float2 a, float2 b) {
    return make_float2(a.x * b.x - a.y * b.y, a.x * b.y + a.y * b.x);
}

// composed 7x7 kernels: kc[(b*2+chain)*49 + (di+3)*7 + (dj+3)] (float2)
__global__ void k_compose(const float* __restrict__ w1r, const float* __restrict__ w1i,
                          const float* __restrict__ w2r, const float* __restrict__ w2i,
                          const float* __restrict__ w3r, const float* __restrict__ w3i,
                          float* __restrict__ kc) {
    int chain = blockIdx.x, b = blockIdx.y;
    int tid = threadIdx.x;  // 128
    __shared__ float2 sW1[4][9], sW2[16][9], sW3[4][9], sW21[4][25];
    // stage kernels in application order: sW1 first conv (1->4), sW2 (4->4),
    // sW3 last (4->1). adj uses conjT: swap ch axes, transpose (p,q), conj.
    for (int idx = tid; idx < 36; idx += 128) {
        int c = idx / 9, s = idx % 9, p = s / 3, q = s % 3;
        if (chain == 0) {
            int i1 = b * 36 + c * 9 + p * 3 + q;
            sW1[c][s] = make_float2(w1r[i1], w1i[i1]);
            sW3[c][s] = make_float2(w3r[i1], w3i[i1]);
        } else {
            int it = b * 36 + c * 9 + q * 3 + p;
            sW1[c][s] = make_float2(w3r[it], -w3i[it]);
            sW3[c][s] = make_float2(w1r[it], -w1i[it]);
        }
    }
    for (int idx = tid; idx < 144; idx += 128) {
        int co = idx / 36, r = idx % 36, ci = r / 9, s = r % 9, p = s / 3, q = s % 3;
        int iw = (chain == 0) ? (b * 144 + co * 36 + ci * 9 + p * 3 + q)
                              : (b * 144 + ci * 36 + co * 9 + q * 3 + p);
        float iv = w2i[iw];
        sW2[co * 4 + ci][s] = make_float2(w2r[iw], (chain == 0) ? iv : -iv);
    }
    __syncthreads();
    // W21[cm](D2) = sum_{b+c=D2} sum_c1 W2[cm,c1](b) * W1[c1](c)
    for (int idx = tid; idx < 100; idx += 128) {
        int cm = idx / 25, r = idx % 25, di = r / 5 - 2, dj = r % 5 - 2;
        float2 acc = make_float2(0.f, 0.f);
        for (int c1 = 0; c1 < 4; ++c1)
            for (int p = 0; p < 3; ++p)
                for (int q = 0; q < 3; ++q) {
                    int ei = di - (p - 1) + 1, ej = dj - (q - 1) + 1;
                    if (ei >= 0 && ei < 3 && ej >= 0 && ej < 3) {
                        float2 t = cmul(sW2[cm * 4 + c1][p * 3 + q], sW1[c1][ei * 3 + ej]);
                        acc.x += t.x; acc.y += t.y;
                    }
                }
        sW21[cm][r] = acc;
    }
    __syncthreads();
    // K(D) = sum_{a+D2=D} sum_cm W3[cm](a) * W21[cm](D2)
    for (int idx = tid; idx < 49; idx += 128) {
        int di = idx / 7 - 3, dj = idx % 7 - 3;
        float2 acc = make_float2(0.f, 0.f);
        for (int cm = 0; cm < 4; ++cm)
            for (int p = 0; p < 3; ++p)
                for (int q = 0; q < 3; ++q) {
                    int ei = di - (p - 1), ej = dj - (q - 1);
                    if (ei >= -2 && ei <= 2 && ej >= -2 && ej <= 2) {
                        float2 t = cmul(sW3[cm][p * 3 + q], sW21[cm][(ei + 2) * 5 + (ej + 2)]);
                        acc.x += t.x; acc.y += t.y;
                    }
                }
        ((float2*)kc)[(b * 2 + chain) * 49 + idx] = acc;
    }
}

// main composed 7x7 conv. block 16x16, per-thread 8-row column sweep
// (128x16 output tile, halo 3). CPLX=false: real input plane (imag=0).
template <bool CPLX>
__global__ __launch_bounds__(256) void k_conv7(
    const float* __restrict__ xr, const float* __restrict__ xi,
    const float* __restrict__ kc, int chain,
    float* __restrict__ outr, float* __restrict__ outi) {
    __shared__ float2 tile[134][23];
    __shared__ float2 kt[49];
    int b = blockIdx.z;
    int tid = threadIdx.y * 16 + threadIdx.x;
    const float2* kb = (const float2*)kc + (b * 2 + chain) * 49;
    for (int idx = tid; idx < 49; idx += 256) kt[idx] = kb[idx];
    int row_base = blockIdx.y * 128 - 3;
    int col_base = blockIdx.x * 16 - 3;
    for (int idx = tid; idx < 134 * 22; idx += 256) {
        int r = idx / 22, c = idx % 22;
        int gr = row_base + r, gc = col_base + c;
        bool in = (gr >= 0 && gr < NGRID && gc >= 0 && gc < NGRID);
        long long g = (long long)b * N2G + (long long)gr * NGRID + gc;
        float vr = in ? xr[g] : 0.0f;
        float vi = (CPLX && in) ? xi[g] : 0.0f;
        tile[r][c] = make_float2(vr, vi);
    }
    __syncthreads();

    int tx = threadIdx.x, r0 = threadIdx.y * 8;
    float2 acc[8];
    #pragma unroll
    for (int r = 0; r < 8; ++r) acc[r] = make_float2(0.f, 0.f);
    #pragma unroll
    for (int t = 0; t < 7; ++t) {
        float2 kv[7];
        #pragma unroll
        for (int s = 0; s < 7; ++s) kv[s] = kt[s * 7 + t];
        #pragma unroll
        for (int rr = 0; rr < 14; ++rr) {
            float2 xv = tile[r0 + rr][tx + t];
            #pragma unroll
            for (int s = 0; s < 7; ++s) {
                int orow = rr - s;
                if (orow >= 0 && orow < 8) {
                    acc[orow].x += kv[s].x * xv.x;
                    acc[orow].y += kv[s].y * xv.x;
                    if (CPLX) {
                        acc[orow].x -= kv[s].y * xv.y;
                        acc[orow].y += kv[s].x * xv.y;
                    }
                }
            }
        }
    }
    int gc = blockIdx.x * 16 + tx;
    if (gc >= NGRID) return;
    #pragma unroll
    for (int r = 0; r < 8; ++r) {
        int gr = blockIdx.y * 128 + r0 + r;
        if (gr < NGRID) {
            long long g = (long long)b * N2G + (long long)gr * NGRID + gc;
            outr[g] = acc[r].x;
            outi[g] = acc[r].y;
        }
    }
}

// exact sequential recompute of the width-2 border ring. one block per
// (64-wide segment, side, batch). sides: 0 top (rows 0,1), 1 bottom
// (rows 512,511), 2 left (cols 0,1; rows 2..510), 3 right (cols 512,511).
// (d,u): d = depth from that border, u = coordinate along it.
template <int CHAIN>
__global__ __launch_bounds__(256) void k_ring7(
    const float* __restrict__ xr, const float* __restrict__ xi,
    const float* __restrict__ w1r, const float* __restrict__ w1i,
    const float* __restrict__ w2r, const float* __restrict__ w2i,
    const float* __restrict__ w3r, const float* __restrict__ w3i,
    float* __restrict__ outr, float* __restrict__ outi) {
    constexpr bool CPLX = (CHAIN == 1);
    __shared__ float2 W1s[4][9], W2s[16][9], W3s[4][9];
    __shared__ float2 Y[4][4][68];   // stage-1 band: d 0..3, u band 68
    __shared__ float2 Z[4][3][66];   // stage-2 band: d 0..2, u band 66
    int side = blockIdx.y, b = blockIdx.z;
    int u0 = blockIdx.x * 64;
    int ulo = (side < 2) ? 0 : 2;
    int uhi = (side < 2) ? (NGRID - 1) : (NGRID - 3);
    if (u0 > uhi) return;
    int tid = threadIdx.x;

    for (int idx = tid; idx < 36; idx += 256) {
        int c = idx / 9, s = idx % 9, p = s / 3, q = s % 3;
        if (CHAIN == 0) {
            int i1 = b * 36 + c * 9 + p * 3 + q;
            W1s[c][s] = make_float2(w1r[i1], w1i[i1]);
            W3s[c][s] = make_float2(w3r[i1], w3i[i1]);
        } else {
            int it = b * 36 + c * 9 + q * 3 + p;
            W1s[c][s] = make_float2(w3r[it], -w3i[it]);
            W3s[c][s] = make_float2(w1r[it], -w1i[it]);
        }
    }
    for (int idx = tid; idx < 144; idx += 256) {
        int co = idx / 36, r = idx % 36, ci = r / 9, s = r % 9, p = s / 3, q = s % 3;
        int iw = (CHAIN == 0) ? (b * 144 + co * 36 + ci * 9 + p * 3 + q)
                              : (b * 144 + ci * 36 + co * 9 + q * 3 + p);
        float iv = w2i[iw];
        W2s[co * 4 + ci][s] = make_float2(w2r[iw], (CHAIN == 0) ? iv : -iv);
    }
    __syncthreads();

    // stage 1: y = conv1(x) on band d 0..3, u in [u0-2, u0+65]; zero outside grid
    for (int idx = tid; idx < 4 * 4 * 68; idx += 256) {
        int ch = idx / (4 * 68), r = idx % (4 * 68), d = r / 68, uu = r % 68;
        int u = u0 - 2 + uu;
        float2 acc = make_float2(0.f, 0.f);
        if (u >= 0 && u < NGRID) {
            int i, j;
            if (side == 0)      { i = d;       j = u; }
            else if (side == 1) { i = 512 - d; j = u; }
            else if (side == 2) { i = u;       j = d; }
            else                { i = u;       j = 512 - d; }
            for (int p = 0; p < 3; ++p)
                for (int q = 0; q < 3; ++q) {
                    int ii = i + p - 1, jj = j + q - 1;
                    if (ii >= 0 && ii < NGRID && jj >= 0 && jj < NGRID) {
                        long long g = (long long)b * N2G + (long long)ii * NGRID + jj;
                        float vr = xr[g];
                        float vi = CPLX ? xi[g] : 0.0f;
                        float2 w = W1s[ch][p * 3 + q];
                        acc.x += w.x * vr - w.y * vi;
                        acc.y += w.x * vi + w.y * vr;
                    }
                }
        }
        Y[ch][d][uu] = acc;
    }
    __syncthreads();

    // stage 2: z = conv2(y), y zeroed outside grid (d2<0 => outside via map)
    for (int idx = tid; idx < 4 * 3 * 66; idx += 256) {
        int co = idx / (3 * 66), r = idx % (3 * 66), d = r / 66, uu = r % 66;
        int u = u0 - 1 + uu;
        float2 acc = make_float2(0.f, 0.f);
        if (u >= 0 && u < NGRID) {
            for (int p = 0; p < 3; ++p)
                for (int q = 0; q < 3; ++q) {
                    int dd, du;
                    if (side == 0)      { dd = p - 1; du = q - 1; }
                    else if (side == 1) { dd = 1 - p; du = q - 1; }
                    else if (side == 2) { dd = q - 1; du = p - 1; }
                    else                { dd = 1 - q; du = p - 1; }
                    int d2 = d + dd, uy = uu + 1 + du;
                    if (d2 >= 0) {
                        for (int ci = 0; ci < 4; ++ci) {
                            float2 yv = Y[ci][d2][uy];
                            float2 w = W2s[co * 4 + ci][p * 3 + q];
                            acc.x += w.x * yv.x - w.y * yv.y;
                            acc.y += w.x * yv.y + w.y * yv.x;
                        }
                    }
                }
        }
        Z[co][d][uu] = acc;
    }
    __syncthreads();

    // stage 3: ring outputs d in {0,1}; overwrite composed values
    for (int idx = tid; idx < 128; idx += 256) {
        int d = idx / 64, uu = idx % 64;
        int u = u0 + uu;
        if (u < ulo || u > uhi) continue;
        float2 acc = make_float2(0.f, 0.f);
        for (int p = 0; p < 3; ++p)
            for (int q = 0; q < 3; ++q) {
                int dd, du;
                if (side == 0)      { dd = p - 1; du = q - 1; }
                else if (side == 1) { dd = 1 - p; du = q - 1; }
                else if (side == 2) { dd = q - 1; du = p - 1; }
                else                { dd = 1 - q; du = p - 1; }
                int d2 = d + dd, uz = uu + 1 + du;
                if (d2 >= 0) {
                    for (int ci = 0; ci < 4; ++ci) {
                        float2 zv = Z[ci][d2][uz];
                        float2 w = W3s[ci][p * 3 + q];
                        acc.x += w.x * zv.x - w.y * zv.y;
                        acc.y += w.x * zv.y + w.y * zv.x;
                    }
                }
            }
        int i, j;
        if (side == 0)      { i = d;       j = u; }
        else if (side == 1) { i = 512 - d; j = u; }
        else if (side == 2) { i = u;       j = d; }
        else                { i = u;       j = 512 - d; }
        long long g = (long long)b * N2G + (long long)i * NGRID + j;
        outr[g] = acc.x;
        outi[g] = acc.y;
    }
}

// o *= wt * ik2  (complex multiply by wt, scale by ik2)
__global__ void k_scale(float* __restrict__ or_, float* __restrict__ oi_,
                        const float* __restrict__ wtr, const float* __restrict__ wti) {
    long long idx = (long long)blockIdx.x * blockDim.x + threadIdx.x;
    if (idx >= (long long)NB * N2G) return;
    int pix = (int)(idx % N2G);
    int u = pix / NGRID, v = pix % NGRID;
    int du = u - 256, dv = v - 256;
    float ik2;
    if (du == 0 && dv == 0)
        ik2 = 1.0f;
    else
        ik2 = (float)(1.0 / (9.869604401089358 * (double)(du * du + dv * dv)));
    float xr = or_[idx], xv = oi_[idx];
    float wrv = wtr[idx], wiv = wti[idx];
    or_[idx] = (xr * wrv - xv * wiv) * ik2;
    oi_[idx] = (xr * wiv + xv * wrv) * ik2;
}

// per-batch: red[2b] += sum(r*e), red[2b+1] += sum(Ae*e)
__global__ void k_dot2(const float* __restrict__ r, const float* __restrict__ e,
                       const float* __restrict__ Ae, float* __restrict__ red) {
    int b = blockIdx.y;
    const float* rb = r + (long long)b * N2G;
    const float* eb = e + (long long)b * N2G;
    const float* ab = Ae + (long long)b * N2G;
    float s1 = 0.0f, s2 = 0.0f;
    for (int i = blockIdx.x * blockDim.x + threadIdx.x; i < N2G;
         i += gridDim.x * blockDim.x) {
        float ev = eb[i];
        s1 += rb[i] * ev;
        s2 += ab[i] * ev;
    }
    #pragma unroll
    for (int o = 32; o > 0; o >>= 1) {
        s1 += __shfl_down(s1, o);
        s2 += __shfl_down(s2, o);
    }
    __shared__ float l1[4], l2[4];
    int wid = threadIdx.x >> 6;
    if ((threadIdx.x & 63) == 0) { l1[wid] = s1; l2[wid] = s2; }
    __syncthreads();
    if (threadIdx.x == 0) {
        atomicAdd(&red[2 * b], l1[0] + l1[1] + l1[2] + l1[3]);
        atomicAdd(&red[2 * b + 1], l2[0] + l2[1] + l2[2] + l2[3]);
    }
}

__global__ void k_update(float* __restrict__ x, const float* __restrict__ e,
                         const float* __restrict__ red) {
    long long idx = (long long)blockIdx.x * blockDim.x + threadIdx.x;
    if (idx >= (long long)NB * N2G) return;
    int b = (int)(idx / N2G);
    float alpha = red[2 * b] / red[2 * b + 1];
    x[idx] += alpha * e[idx];
}

__global__ void k_norm(const float* __restrict__ r, const float* __restrict__ f,
                       float* __restrict__ red) {
    float s1 = 0.0f, s2 = 0.0f;
    for (long long i = (long long)blockIdx.x * blockDim.x + threadIdx.x;
         i < (long long)NB * N2G; i += (long long)gridDim.x * blockDim.x) {
        float rv = r[i], fv = f[i];
        s1 += rv * rv;
        s2 += fv * fv;
    }
    #pragma unroll
    for (int o = 32; o > 0; o >>= 1) {
        s1 += __shfl_down(s1, o);
        s2 += __shfl_down(s2, o);
    }
    __shared__ float l1[4], l2[4];
    int wid = threadIdx.x >> 6;
    if ((threadIdx.x & 63) == 0) { l1[wid] = s1; l2[wid] = s2; }
    __syncthreads();
    if (threadIdx.x == 0) {
        atomicAdd(&red[8], l1[0] + l1[1] + l1[2] + l1[3]);
        atomicAdd(&red[9], l2[0] + l2[1] + l2[2] + l2[3]);
    }
}

__global__ void k_final(const float* __restrict__ red, float* __restrict__ out) {
    out[0] = sqrtf(red[8] / red[9]);
}

// ---------------------------------------------------------------------------
extern "C" void kernel_launch(void* const* d_in, const int* in_sizes, int n_in,
                              void* d_out, int out_size, void* d_ws, size_t ws_size,
                              hipStream_t stream) {
    (void)in_sizes; (void)n_in; (void)out_size; (void)ws_size;
    const float* f    = (const float*)d_in[0];
    const float* coef = (const float*)d_in[1];
    const float* w1r  = (const float*)d_in[3];
    const float* w1i  = (const float*)d_in[4];
    const float* w2r  = (const float*)d_in[5];
    const float* w2i  = (const float*)d_in[6];
    const float* w3r  = (const float*)d_in[7];
    const float* w3i  = (const float*)d_in[8];
    const float* wtr  = (const float*)d_in[9];
    const float* wti  = (const float*)d_in[10];
    float* out = (float*)d_out;

    float* ws = (float*)d_ws;
    size_t off = 0;
    auto alloc = [&](long long n) {
        float* p = ws + off;
        off += (size_t)((n + 3) & ~3LL);
        return p;
    };
    float* x0   = alloc((long long)NB * N2G);
    float* x1   = alloc((long long)NB * N2G);
    float* rr   = alloc((long long)NB * N2G);
    float* ee   = alloc((long long)NB * N2G);
    float* rh   = alloc((long long)NB * N2G);
    float* dinv = alloc((long long)NB * NI2);
    float* c1r  = alloc((long long)NB * 4 * N2G);
    float* c1i  = alloc((long long)NB * 4 * N2G);
    float* c2r  = alloc((long long)NB * 4 * N2G);
    float* c2i  = alloc((long long)NB * 4 * N2G);
    float* pr   = c1r;  // partial span (c1r..c2i contiguous)
    float* or_  = alloc((long long)NB * N2G);
    float* oi_  = alloc((long long)NB * N2G);
    float* red  = alloc(16);
    ushort* sGh  = (ushort*)alloc(513 * 512 / 2);
    ushort* sGl  = (ushort*)alloc(513 * 512 / 2);
    ushort* sGth = (ushort*)alloc(513 * 512 / 2);
    ushort* sGtl = (ushort*)alloc(513 * 512 / 2);
    ushort* sFAh = (ushort*)alloc(511 * 1056 / 2);
    ushort* sFAl = (ushort*)alloc(511 * 1056 / 2);
    ushort* sFBh = (ushort*)alloc(1022 * 1056 / 2);
    ushort* sFBl = (ushort*)alloc(1022 * 1056 / 2);
    ushort* dAh  = (ushort*)alloc((long long)NB * 513 * 1056 / 2);
    ushort* dAl  = (ushort*)alloc((long long)NB * 513 * 1056 / 2);
    ushort* dBh  = (ushort*)alloc((long long)NB * 511 * 1056 / 2);
    ushort* dBl  = (ushort*)alloc((long long)NB * 511 * 1056 / 2);
    float* kcomp = alloc(NB * 2 * 49 * 2);   // composed 7x7 chain kernels
    float* Ae   = rh;  // rh is dead after the forward conv reads it

    dim3 blk2(16, 16);
    dim3 grdS(33, 33, NB);
    dim3 grdC(33, 5, NB);    // conv7: 16x128 output tile per block
    dim3 grdR(9, 4, NB);     // ring7: 64-wide segments x 4 sides
    const int SP = 4;        // split-K (validated R15)

    hipMemsetAsync(x0, 0, (size_t)NB * N2G * sizeof(float), stream);
    k_dinv<<<dim3((NB * NI2 + 255) / 256), dim3(256), 0, stream>>>(coef, dinv);
    k_genDSTA<<<dim3((513 * 512 + 255) / 256), dim3(256), 0, stream>>>(sGh, sGl);
    k_genDSTB<<<dim3((513 * 512 + 255) / 256), dim3(256), 0, stream>>>(sGth, sGtl);
    k_genFA<<<dim3((511 * 1056 + 255) / 256), dim3(256), 0, stream>>>(sFAh, sFAl);
    k_genFB<<<dim3((1022 * 1056 + 255) / 256), dim3(256), 0, stream>>>(sFBh, sFBl);
    k_compose<<<dim3(2, NB), dim3(128), 0, stream>>>(w1r, w1i, w2r, w2i, w3r, w3i, kcomp);

    float* xa = x0;
    float* xb = x1;
    for (int step = 0; step < 2; ++step) {
        // 10 weighted-Jacobi sweeps as 2 fused 5-sweep launches
        for (int it = 0; it < 2; ++it) {
            k_jacobi5<<<grdS, blk2, 0, stream>>>(xa, coef, f, dinv, xb);
            float* t = xa; xa = xb; xb = t;
        }
        k_stencil<<<grdS, blk2, 0, stream>>>(xa, coef, f, nullptr, rr, 0);

        // ---- H_apply (all GEMMs via MFMA split-bf16) ----
        // gemm1: t2 = G(513x511) * rI(511x511); B^T from rr interior
        k_cvtBt<<<dim3((511 * 512 + 255) / 256, NB), dim3(256), 0, stream>>>(
            rr + NGRID + 1, N2G, NGRID, 511, 511, 512, dBh, dBl);
        k_mgemm<<<dim3(4, 5, NB * SP), dim3(256), 0, stream>>>(
            sGh, sGl, 0, dBh, dBl, (long long)511 * 512,
            pr, (long long)NTT, 513, 511, 512, SP);
        k_redA<<<dim3(1026, NB), dim3(256), 0, stream>>>(pr, SP, dAh, dAl);
        // gemm2: rh = t2(513x511) * Gt(511x513)
        k_mgemm<<<dim3(5, 5, NB * SP), dim3(256), 0, stream>>>(
            dAh, dAl, (long long)513 * 512, sGth, sGtl, 0,
            pr, (long long)N2G, 513, 513, 512, SP);
        k_reduce<<<dim3(1024, NB), dim3(256), 0, stream>>>(
            pr, rh, N2G, NGRID, NGRID, (long long)N2G, SP);

        // forward conv chain == one complex 7x7 (real input rh)
        k_conv7<false><<<grdC, blk2, 0, stream>>>(rh, nullptr, kcomp, 0, or_, oi_);
        k_ring7<0><<<grdR, dim3(256), 0, stream>>>(
            rh, nullptr, w1r, w1i, w2r, w2i, w3r, w3i, or_, oi_);
        k_scale<<<dim3((NB * N2G + 255) / 256), dim3(256), 0, stream>>>(or_, oi_, wtr, wti);
        // adjoint conv chain == one complex 7x7 (complex input)
        k_conv7<true><<<grdC, blk2, 0, stream>>>(or_, oi_, kcomp, 1, c1r, c1i);
        k_ring7<1><<<grdR, dim3(256), 0, stream>>>(
            or_, oi_, w1r, w1i, w2r, w2i, w3r, w3i, c1r, c1i);

        // gemm3' (transposed): P'[n<1022][m<513] = sFB * [c1r|c1i]^T
        k_cvtA<<<dim3((513 * 1056 + 255) / 256, NB), dim3(256), 0, stream>>>(
            c1r, c1i, N2G, N2G, NGRID, NGRID, 513, 513, 1026, 1056, dAh, dAl);
        k_mgemm<<<dim3(5, 8, NB * 4), dim3(256), 0, stream>>>(
            sFBh, sFBl, 0, dAh, dAl, (long long)513 * 1056,
            pr, 1022LL * 513, 1022, 513, 1056, 4);
        k_redBt<<<dim3(2109, NB), dim3(256), 0, stream>>>(pr, 4, dBh, dBl);
        // gemm4: e = [Fr|Fi](511x1026) * [t2r;-t2i](1026x511)
        k_mgemm<<<dim3(4, 4, NB * SP), dim3(256), 0, stream>>>(
            sFAh, sFAl, 0, dBh, dBl, (long long)511 * 1056,
            pr, (long long)NI2, 511, 511, 1056, SP);
        hipMemsetAsync(ee, 0, (size_t)NB * N2G * sizeof(float), stream);
        k_reduce<<<dim3(1024, NB), dim3(256), 0, stream>>>(
            pr, ee + NGRID + 1, NI2, NINT, NGRID, (long long)N2G, SP);

        // Ae = A e ; alpha = (r.e)/(Ae.e) ; x += alpha e
        k_stencil<<<grdS, blk2, 0, stream>>>(ee, coef, nullptr, nullptr, Ae, 2);
        hipMemsetAsync(red, 0, 8 * sizeof(float), stream);
        k_dot2<<<dim3(64, NB), dim3(256), 0, stream>>>(rr, ee, Ae, red);
        k_update<<<dim3((NB * N2G + 255) / 256), dim3(256), 0, stream>>>(xa, ee, red);
    }
    k_stencil<<<grdS, blk2, 0, stream>>>(xa, coef, f, nullptr, rr, 0);
    hipMemsetAsync(red + 8, 0, 2 * sizeof(float), stream);
    k_norm<<<dim3(256), dim3(256), 0, stream>>>(rr, f, red);
    k_final<<<dim3(1), dim3(1), 0, stream>>>(red, out);
}

// Round 2
// 721.023 us; speedup vs baseline: 1.2093x; 1.0430x over previous
//
#include <hip/hip_runtime.h>
#include <math.h>

#ifndef M_PI
#define M_PI 3.14159265358979323846
#endif

#define NGRID 513
#define NCELL 512
#define NINT  511
#define NB    4

constexpr int N2G = NGRID * NGRID;   // 263169
constexpr int NI2 = NINT * NINT;     // 261121
constexpr int NQ  = 257 * 257;       // 66049 (rh antisym quadrant)

typedef unsigned short ushort;
typedef unsigned int uint32;
typedef __attribute__((ext_vector_type(8))) short short8;
typedef __attribute__((ext_vector_type(8))) unsigned short ushort8;
typedef __attribute__((ext_vector_type(4))) float f32x4;

// ---------------------------------------------------------------------------
// bf16 split helpers (RNE)
// ---------------------------------------------------------------------------
__device__ __forceinline__ ushort f2bf(float x) {
    unsigned u = __float_as_uint(x);
    unsigned r = u + 0x7FFFu + ((u >> 16) & 1u);
    return (ushort)(r >> 16);
}
__device__ __forceinline__ float bf2f(ushort h) {
    return __uint_as_float(((unsigned)h) << 16);
}

// rh antisymmetric-quadrant read: rq = batch base (257x257), (i,j) full-grid.
// rh[256+d] = -rh[256-d] exactly (DST row negation is IEEE-exact).
__device__ __forceinline__ float rhq_read(const float* __restrict__ rq,
                                          int i, int j) {
    float s = 1.0f;
    if (i > 256) { i = 512 - i; s = -s; }
    if (j > 256) { j = 512 - j; s = -s; }
    return s * rq[i * 257 + j];
}

// wt * ik2 complex scale (bitwise-identical to the old k_scale expression)
__device__ __forceinline__ float2 scale_wt(float x0, float x1, float wr, float wi,
                                           int gr, int gc) {
    int du = gr - 256, dv = gc - 256;
    float ik2;
    if (du == 0 && dv == 0)
        ik2 = 1.0f;
    else
        ik2 = (float)(1.0 / (9.869604401089358 * (double)(du * du + dv * dv)));
    return make_float2((x0 * wr - x1 * wi) * ik2, (x0 * wi + x1 * wr) * ik2);
}

// ---------------------------------------------------------------------------
// FEM Darcy operator at interior node (i,j), i,j in 1..511
// ---------------------------------------------------------------------------
__device__ __forceinline__ float darcyA(const float* __restrict__ x,
                                        const float* __restrict__ a,
                                        int i, int j) {
    const float c23 = 2.0f / 3.0f, c16 = 1.0f / 6.0f, c13 = 1.0f / 3.0f;
    float a00 = a[(i - 1) * NCELL + (j - 1)];
    float a01 = a[(i - 1) * NCELL + j];
    float a10 = a[i * NCELL + (j - 1)];
    float a11 = a[i * NCELL + j];
    const float* xm = x + (i - 1) * NGRID;
    const float* xc = x + i * NGRID;
    const float* xp = x + (i + 1) * NGRID;
    return c23 * (a00 + a01 + a10 + a11) * xc[j]
         - c16 * ((a00 + a01) * xm[j] + (a10 + a11) * xp[j]
                + (a00 + a10) * xc[j - 1] + (a01 + a11) * xc[j + 1])
         - c13 * (a00 * xm[j - 1] + a01 * xm[j + 1]
                + a10 * xp[j - 1] + a11 * xp[j + 1]);
}

// mode 0: out = f - A x (+ optional fused bf16 transpose planes for gemm1 B)
// mode 2: out = A x (interior), 0 boundary
__global__ void k_stencil(const float* __restrict__ xin,
                          const float* __restrict__ a,
                          const float* __restrict__ f,
                          float* __restrict__ out, int mode,
                          ushort* __restrict__ tBh, ushort* __restrict__ tBl) {
    __shared__ float st[16][17];
    int b = blockIdx.z;
    int j = blockIdx.x * 16 + threadIdx.x;
    int i = blockIdx.y * 16 + threadIdx.y;
    const float* xb = xin + (long long)b * N2G;
    const float* ab = a + (long long)b * NCELL * NCELL;
    bool ingrid = (i < NGRID && j < NGRID);
    bool interior = ingrid && i >= 1 && i <= NINT && j >= 1 && j <= NINT;
    float v = 0.0f;
    long long idx = (long long)b * N2G + (long long)i * NGRID + j;
    if (interior) {
        float Ax = darcyA(xb, ab, i, j);
        v = (mode == 0) ? f[idx] - Ax : Ax;
    } else if (ingrid) {
        v = (mode == 0) ? f[idx] : 0.0f;
    }
    if (ingrid) out[idx] = v;
    if (mode == 0 && tBh) {
        st[threadIdx.y][threadIdx.x] = v;
        __syncthreads();
        int tx = threadIdx.x, ty = threadIdx.y;
        int i2 = blockIdx.y * 16 + tx;   // = k+1
        int j2 = blockIdx.x * 16 + ty;   // = n+1
        if (i2 >= 1 && i2 <= NINT && j2 >= 1 && j2 <= NINT) {
            float rv = st[tx][ty];
            ushort h = f2bf(rv);
            long long o = (long long)b * 511 * 512
                        + (long long)(j2 - 1) * 512 + (i2 - 1);
            tBh[o] = h;
            tBl[o] = f2bf(rv - bf2f(h));
        }
    }
}

// ---------------------------------------------------------------------------
// 5 fused weighted-Jacobi sweeps per launch (halo 5, LDS ping-pong stages).
// ---------------------------------------------------------------------------
__global__ void k_jacobi5(const float* __restrict__ xin,
                          const float* __restrict__ a,
                          const float* __restrict__ f,
                          const float* __restrict__ dinv,
                          float* __restrict__ out) {
    __shared__ float sx[26][26];
    __shared__ float sa[25][26];
    __shared__ float sf[24][24];
    __shared__ float sd[24][24];
    __shared__ float sp[2][24][26];
    const float c23 = 2.0f / 3.0f, c16 = 1.0f / 6.0f, c13 = 1.0f / 3.0f;
    int b = blockIdx.z;
    const float* xb = xin + (long long)b * N2G;
    const float* ab = a + (long long)b * NCELL * NCELL;
    const float* fb = f + (long long)b * N2G;
    const float* db = dinv + (long long)b * NI2;
    int ox = blockIdx.x * 16, oy = blockIdx.y * 16;
    int tx = threadIdx.x, ty = threadIdx.y;
    int tid = ty * 16 + tx;

    for (int idx = tid; idx < 26 * 26; idx += 256) {
        int ly = idx / 26, lx = idx % 26;
        int gy = oy - 5 + ly, gx = ox - 5 + lx;
        bool in = (gy >= 0 && gy < NGRID && gx >= 0 && gx < NGRID);
        sx[ly][lx] = in ? xb[(long long)gy * NGRID + gx] : 0.0f;
    }
    for (int idx = tid; idx < 25 * 25; idx += 256) {
        int ly = idx / 25, lx = idx % 25;
        int gy = oy - 5 + ly, gx = ox - 5 + lx;
        bool in = (gy >= 0 && gy < NCELL && gx >= 0 && gx < NCELL);
        sa[ly][lx] = in ? ab[(long long)gy * NCELL + gx] : 0.0f;
    }
    for (int idx = tid; idx < 24 * 24; idx += 256) {
        int ly = idx / 24, lx = idx % 24;
        int gy = oy - 4 + ly, gx = ox - 4 + lx;
        bool ing = (gy >= 0 && gy < NGRID && gx >= 0 && gx < NGRID);
        bool itr = (gy >= 1 && gy <= NINT && gx >= 1 && gx <= NINT);
        sf[ly][lx] = ing ? fb[(long long)gy * NGRID + gx] : 0.0f;
        sd[ly][lx] = itr ? db[(long long)(gy - 1) * NINT + (gx - 1)] : 0.0f;
    }
    __syncthreads();

    for (int idx = tid; idx < 24 * 24; idx += 256) {
        int ly = idx / 24, lx = idx % 24;
        int gy = oy - 4 + ly, gx = ox - 4 + lx;
        float v = 0.0f;
        if (gy >= 0 && gy < NGRID && gx >= 0 && gx < NGRID) {
            float xc = sx[ly + 1][lx + 1];
            if (gy >= 1 && gy <= NINT && gx >= 1 && gx <= NINT) {
                float a00 = sa[ly][lx], a01 = sa[ly][lx + 1];
                float a10 = sa[ly + 1][lx], a11 = sa[ly + 1][lx + 1];
                float Ax = c23 * (a00 + a01 + a10 + a11) * xc
                    - c16 * ((a00 + a01) * sx[ly][lx + 1] + (a10 + a11) * sx[ly + 2][lx + 1]
                           + (a00 + a10) * sx[ly + 1][lx] + (a01 + a11) * sx[ly + 1][lx + 2])
                    - c13 * (a00 * sx[ly][lx] + a01 * sx[ly][lx + 2]
                           + a10 * sx[ly + 2][lx] + a11 * sx[ly + 2][lx + 2]);
                v = xc + 0.75f * sd[ly][lx] * (sf[ly][lx] - Ax);
            } else {
                v = xc;
            }
        }
        sp[0][ly][lx] = v;
    }
    __syncthreads();

    #pragma unroll 1
    for (int s = 2; s <= 4; ++s) {
        int sz = 24 - 2 * (s - 1);
        int cur = (s - 1) & 1, prv = s & 1;
        for (int idx = tid; idx < sz * sz; idx += 256) {
            int ly = idx / sz, lx = idx % sz;
            int gy = oy - (5 - s) + ly, gx = ox - (5 - s) + lx;
            float v = 0.0f;
            if (gy >= 0 && gy < NGRID && gx >= 0 && gx < NGRID) {
                float xc = sp[prv][ly + 1][lx + 1];
                if (gy >= 1 && gy <= NINT && gx >= 1 && gx <= NINT) {
                    int ar = ly + s - 1, ac = lx + s - 1;
                    float a00 = sa[ar][ac], a01 = sa[ar][ac + 1];
                    float a10 = sa[ar + 1][ac], a11 = sa[ar + 1][ac + 1];
                    float Ax = c23 * (a00 + a01 + a10 + a11) * xc
                        - c16 * ((a00 + a01) * sp[prv][ly][lx + 1] + (a10 + a11) * sp[prv][ly + 2][lx + 1]
                               + (a00 + a10) * sp[prv][ly + 1][lx] + (a01 + a11) * sp[prv][ly + 1][lx + 2])
                        - c13 * (a00 * sp[prv][ly][lx] + a01 * sp[prv][ly][lx + 2]
                               + a10 * sp[prv][ly + 2][lx] + a11 * sp[prv][ly + 2][lx + 2]);
                    int fr = ly + s - 1, fc = lx + s - 1;
                    v = xc + 0.75f * sd[fr][fc] * (sf[fr][fc] - Ax);
                } else {
                    v = xc;
                }
            }
            sp[cur][ly][lx] = v;
        }
        __syncthreads();
    }

    {
        int gy = oy + ty, gx = ox + tx;
        if (gy < NGRID && gx < NGRID) {
            float v;
            float xc = sp[1][ty + 1][tx + 1];
            if (gy >= 1 && gy <= NINT && gx >= 1 && gx <= NINT) {
                int ar = ty + 4, ac = tx + 4;
                float a00 = sa[ar][ac], a01 = sa[ar][ac + 1];
                float a10 = sa[ar + 1][ac], a11 = sa[ar + 1][ac + 1];
                float Ax = c23 * (a00 + a01 + a10 + a11) * xc
                    - c16 * ((a00 + a01) * sp[1][ty][tx + 1] + (a10 + a11) * sp[1][ty + 2][tx + 1]
                           + (a00 + a10) * sp[1][ty + 1][tx] + (a01 + a11) * sp[1][ty + 1][tx + 2])
                    - c13 * (a00 * sp[1][ty][tx] + a01 * sp[1][ty][tx + 2]
                           + a10 * sp[1][ty + 2][tx] + a11 * sp[1][ty + 2][tx + 2]);
                v = xc + 0.75f * sd[ty + 4][tx + 4] * (sf[ty + 4][tx + 4] - Ax);
            } else {
                v = xc;
            }
            out[(long long)b * N2G + (long long)gy * NGRID + gx] = v;
        }
    }
}

__global__ void k_dinv(const float* __restrict__ a, float* __restrict__ dinv) {
    long long idx = (long long)blockIdx.x * blockDim.x + threadIdx.x;
    if (idx >= (long long)NB * NI2) return;
    int b = (int)(idx / NI2);
    int rem = (int)(idx % NI2);
    int p = rem / NINT, q = rem % NINT;
    const float* ab = a + (long long)b * NCELL * NCELL;
    float s = ab[p * NCELL + q] + ab[p * NCELL + q + 1]
            + ab[(p + 1) * NCELL + q] + ab[(p + 1) * NCELL + q + 1];
    dinv[idx] = 1.0f / ((2.0f / 3.0f) * s);
}

// ---------------------------------------------------------------------------
// Static bf16 matrix generation (hi/lo planes, K-padded, integer arg reduce)
// ---------------------------------------------------------------------------
__device__ __forceinline__ void wsplit(double v, ushort* Dh, ushort* Dl, int idx) {
    float vf = (float)v;
    ushort h = f2bf(vf);
    Dh[idx] = h;
    Dl[idx] = f2bf(vf - bf2f(h));
}

__global__ void k_genDSTA(ushort* __restrict__ Dh, ushort* __restrict__ Dl) {
    int idx = blockIdx.x * 256 + threadIdx.x;
    if (idx >= 513 * 512) return;
    int u = idx / 512, k = idx % 512;
    double v = 0.0;
    if (k < 511) {
        int t = ((u - 256) * (k + 1)) % 1024;
        if (t < 0) t += 1024;
        v = sin((M_PI / 512.0) * (double)t);
    }
    wsplit(v, Dh, Dl, idx);
}

__global__ void k_genDSTB(ushort* __restrict__ Dh, ushort* __restrict__ Dl) {
    int idx = blockIdx.x * 256 + threadIdx.x;
    if (idx >= 513 * 512) return;
    int v = idx / 512, k = idx % 512;
    double val = 0.0;
    if (k < 511) {
        int t = ((v - 256) * (k + 1)) % 1024;
        if (t < 0) t += 1024;
        val = sin((M_PI / 512.0) * (double)t) * (-1.0 / 262144.0);
    }
    wsplit(val, Dh, Dl, idx);
}

__global__ void k_genFA(ushort* __restrict__ Dh, ushort* __restrict__ Dl) {
    int idx = blockIdx.x * 256 + threadIdx.x;
    if (idx >= 511 * 1056) return;
    int y = idx / 1056, k = idx % 1056;
    double v = 0.0;
    if (k < 1026) {
        int m = (k < 513) ? k : (k - 513);
        long t = ((long)y * (m - 255)) % 1025;
        if (t < 0) t += 1025;
        double ang = (2.0 * M_PI / 1025.0) * (double)t;
        v = (k < 513) ? cos(ang) : -sin(ang);
    }
    wsplit(v, Dh, Dl, idx);
}

__global__ void k_genFB(ushort* __restrict__ Dh, ushort* __restrict__ Dl) {
    int idx = blockIdx.x * 256 + threadIdx.x;
    if (idx >= 1022 * 1056) return;
    int n = idx / 1056, k = idx % 1056;
    double v = 0.0;
    if (k < 1026) {
        int m = (k < 513) ? k : (k - 513);
        int y = (n < 511) ? n : (n - 511);
        long t = ((long)y * (m - 255)) % 1025;
        if (t < 0) t += 1025;
        double ang = (2.0 * M_PI / 1025.0) * (double)t;
        bool ktop = (k < 513), nleft = (n < 511);
        if (ktop && nleft)        v = cos(ang);
        else if (ktop && !nleft)  v = -sin(ang);
        else if (!ktop && nleft)  v = sin(ang);
        else                      v = cos(ang);
    }
    wsplit(v, Dh, Dl, idx);
}

// ---------------------------------------------------------------------------
// Fused split-K reduce + bf16 convert (GEMM->GEMM handoffs).
// ---------------------------------------------------------------------------
__global__ void k_redA(const float* __restrict__ P, int nsplit, int Mr,
                       ushort* __restrict__ Dh, ushort* __restrict__ Dl) {
    int b = blockIdx.y;
    int idx = blockIdx.x * 256 + threadIdx.x;
    if (idx >= Mr * 512) return;
    int m = idx / 512, k = idx % 512;
    float v = 0.0f;
    if (k < 511) {
        long long base = (long long)m * 511 + k;
        long long str = (long long)Mr * 511;
        #pragma unroll 4
        for (int s = 0; s < nsplit; ++s)
            v += P[((long long)b * nsplit + s) * str + base];
    }
    long long o = (long long)b * Mr * 512 + idx;
    ushort h = f2bf(v);
    Dh[o] = h;
    Dl[o] = f2bf(v - bf2f(h));
}

__global__ void k_redBt(const float* __restrict__ P, int nsplit,
                        ushort* __restrict__ Dh, ushort* __restrict__ Dl) {
    int b = blockIdx.y;
    int idx = blockIdx.x * 256 + threadIdx.x;
    if (idx >= 511 * 1056) return;
    int n = idx / 1056, k = idx % 1056;
    float v = 0.0f;
    if (k < 1026) {
        int row = (k < 513) ? n : (511 + n);
        int col = (k < 513) ? k : (k - 513);
        long long base = (long long)row * 513 + col;
        float acc = 0.0f;
        #pragma unroll 4
        for (int s = 0; s < nsplit; ++s)
            acc += P[((long long)b * nsplit + s) * (1022LL * 513) + base];
        v = (k < 513) ? acc : -acc;
    }
    long long o = (long long)b * 511 * 1056 + idx;
    ushort h = f2bf(v);
    Dh[o] = h;
    Dl[o] = f2bf(v - bf2f(h));
}

// ---------------------------------------------------------------------------
// MFMA real GEMM, 3-term split-bf16 (hh + hl + lh), 16x16x32 bf16 MFMA.
// ---------------------------------------------------------------------------
__global__ __launch_bounds__(256) void k_mgemm(
    const ushort* __restrict__ Ah, const ushort* __restrict__ Al, long long bsA,
    const ushort* __restrict__ Bh, const ushort* __restrict__ Bl, long long bsB,
    float* __restrict__ C, long long bsC,
    int M, int N, int Kp, int nsplit) {
    __shared__ ushort sAh[128 * 40];
    __shared__ ushort sAl[128 * 40];
    __shared__ ushort sBh[128 * 40];
    __shared__ ushort sBl[128 * 40];

    int bz = blockIdx.z, b = bz / nsplit, ks = bz % nsplit;
    int kchunk = (((Kp + nsplit - 1) / nsplit) + 31) & ~31;
    int kbeg = ks * kchunk;
    int kend = min(Kp, kbeg + kchunk);

    Ah += b * bsA; Al += b * bsA;
    Bh += b * bsB; Bl += b * bsB;
    C += ((long long)b * nsplit + ks) * bsC;

    int bm = blockIdx.y * 128, bn = blockIdx.x * 128;
    int tid = threadIdx.x;
    int wave = tid >> 6, lane = tid & 63;
    int wm = (wave >> 1) * 64, wn = (wave & 1) * 64;
    int quad = lane >> 4, l16 = lane & 15;

    f32x4 zf = {0.f, 0.f, 0.f, 0.f};
    f32x4 acc[4][4];
    #pragma unroll
    for (int i = 0; i < 4; ++i)
        #pragma unroll
        for (int j = 0; j < 4; ++j) acc[i][j] = zf;

    int srow = tid >> 2;
    int sk8 = (tid & 3) * 8;

    for (int kt = kbeg; kt < kend; kt += 32) {
        #pragma unroll
        for (int h = 0; h < 2; ++h) {
            int row = srow + 64 * h;
            ushort8 vh = {0, 0, 0, 0, 0, 0, 0, 0};
            ushort8 vl = {0, 0, 0, 0, 0, 0, 0, 0};
            int gm = bm + row;
            if (gm < M) {
                vh = *(const ushort8*)(Ah + (long long)gm * Kp + kt + sk8);
                vl = *(const ushort8*)(Al + (long long)gm * Kp + kt + sk8);
            }
            *(ushort8*)(sAh + row * 40 + sk8) = vh;
            *(ushort8*)(sAl + row * 40 + sk8) = vl;
            ushort8 wh = {0, 0, 0, 0, 0, 0, 0, 0};
            ushort8 wl = {0, 0, 0, 0, 0, 0, 0, 0};
            int gn = bn + row;
            if (gn < N) {
                wh = *(const ushort8*)(Bh + (long long)gn * Kp + kt + sk8);
                wl = *(const ushort8*)(Bl + (long long)gn * Kp + kt + sk8);
            }
            *(ushort8*)(sBh + row * 40 + sk8) = wh;
            *(ushort8*)(sBl + row * 40 + sk8) = wl;
        }
        __syncthreads();

        short8 afh[4], afl[4], bfh[4], bfl[4];
        #pragma unroll
        for (int t = 0; t < 4; ++t) {
            int ar = wm + t * 16 + l16;
            afh[t] = *(const short8*)(sAh + ar * 40 + quad * 8);
            afl[t] = *(const short8*)(sAl + ar * 40 + quad * 8);
            int br = wn + t * 16 + l16;
            bfh[t] = *(const short8*)(sBh + br * 40 + quad * 8);
            bfl[t] = *(const short8*)(sBl + br * 40 + quad * 8);
        }
        #pragma unroll
        for (int mt = 0; mt < 4; ++mt)
            #pragma unroll
            for (int nt = 0; nt < 4; ++nt) {
                acc[mt][nt] = __builtin_amdgcn_mfma_f32_16x16x32_bf16(
                    afh[mt], bfh[nt], acc[mt][nt], 0, 0, 0);
                acc[mt][nt] = __builtin_amdgcn_mfma_f32_16x16x32_bf16(
                    afh[mt], bfl[nt], acc[mt][nt], 0, 0, 0);
                acc[mt][nt] = __builtin_amdgcn_mfma_f32_16x16x32_bf16(
                    afl[mt], bfh[nt], acc[mt][nt], 0, 0, 0);
            }
        __syncthreads();
    }

    #pragma unroll
    for (int mt = 0; mt < 4; ++mt) {
        #pragma unroll
        for (int r = 0; r < 4; ++r) {
            int gm = bm + wm + mt * 16 + quad * 4 + r;
            if (gm >= M) continue;
            long long rowoff = (long long)gm * N;
            #pragma unroll
            for (int nt = 0; nt < 4; ++nt) {
                int gn = bn + wn + nt * 16 + l16;
                if (gn < N) C[rowoff + gn] = acc[mt][nt][r];
            }
        }
    }
}

// ---------------------------------------------------------------------------
// Sum nsplit dense [M x N] partials -> strided fp32 output (row stride ldo).
// ---------------------------------------------------------------------------
__global__ void k_reduce(const float* __restrict__ Pr,
                         float* __restrict__ outR,
                         int MN, int N, int ldo, long long bsOut, int nsplit) {
    int b = blockIdx.y;
    for (int idx = blockIdx.x * 256 + threadIdx.x; idx < MN;
         idx += gridDim.x * 256) {
        float sr = 0.0f;
        #pragma unroll 4
        for (int s = 0; s < nsplit; ++s)
            sr += Pr[((long long)b * nsplit + s) * MN + idx];
        int m = idx / N, n = idx - m * N;
        outR[(long long)b * bsOut + (long long)m * ldo + n] = sr;
    }
}

// ---------------------------------------------------------------------------
// Composed conv-chain (validated R17): each 3-conv chain == one complex 7x7.
// ---------------------------------------------------------------------------
__device__ __forceinline__ float2 cmul(float2 a, float2 b) {
    return make_float2(a.x * b.x - a.y * b.y, a.x * b.y + a.y * b.x);
}

// composed 7x7 kernels: kc[(b*2+chain)*49 + (di+3)*7 + (dj+3)] (float2)
__global__ void k_compose(const float* __restrict__ w1r, const float* __restrict__ w1i,
                          const float* __restrict__ w2r, const float* __restrict__ w2i,
                          const float* __restrict__ w3r, const float* __restrict__ w3i,
                          float* __restrict__ kc) {
    int chain = blockIdx.x, b = blockIdx.y;
    int tid = threadIdx.x;  // 128
    __shared__ float2 sW1[4][9], sW2[16][9], sW3[4][9], sW21[4][25];
    for (int idx = tid; idx < 36; idx += 128) {
        int c = idx / 9, s = idx % 9, p = s / 3, q = s % 3;
        if (chain == 0) {
            int i1 = b * 36 + c * 9 + p * 3 + q;
            sW1[c][s] = make_float2(w1r[i1], w1i[i1]);
            sW3[c][s] = make_float2(w3r[i1], w3i[i1]);
        } else {
            int it = b * 36 + c * 9 + q * 3 + p;
            sW1[c][s] = make_float2(w3r[it], -w3i[it]);
            sW3[c][s] = make_float2(w1r[it], -w1i[it]);
        }
    }
    for (int idx = tid; idx < 144; idx += 128) {
        int co = idx / 36, r = idx % 36, ci = r / 9, s = r % 9, p = s / 3, q = s % 3;
        int iw = (chain == 0) ? (b * 144 + co * 36 + ci * 9 + p * 3 + q)
                              : (b * 144 + ci * 36 + co * 9 + q * 3 + p);
        float iv = w2i[iw];
        sW2[co * 4 + ci][s] = make_float2(w2r[iw], (chain == 0) ? iv : -iv);
    }
    __syncthreads();
    for (int idx = tid; idx < 100; idx += 128) {
        int cm = idx / 25, r = idx % 25, di = r / 5 - 2, dj = r % 5 - 2;
        float2 acc = make_float2(0.f, 0.f);
        for (int c1 = 0; c1 < 4; ++c1)
            for (int p = 0; p < 3; ++p)
                for (int q = 0; q < 3; ++q) {
                    int ei = di - (p - 1) + 1, ej = dj - (q - 1) + 1;
                    if (ei >= 0 && ei < 3 && ej >= 0 && ej < 3) {
                        float2 t = cmul(sW2[cm * 4 + c1][p * 3 + q], sW1[c1][ei * 3 + ej]);
                        acc.x += t.x; acc.y += t.y;
                    }
                }
        sW21[cm][r] = acc;
    }
    __syncthreads();
    for (int idx = tid; idx < 49; idx += 128) {
        int di = idx / 7 - 3, dj = idx % 7 - 3;
        float2 acc = make_float2(0.f, 0.f);
        for (int cm = 0; cm < 4; ++cm)
            for (int p = 0; p < 3; ++p)
                for (int q = 0; q < 3; ++q) {
                    int ei = di - (p - 1), ej = dj - (q - 1);
                    if (ei >= -2 && ei <= 2 && ej >= -2 && ej <= 2) {
                        float2 t = cmul(sW3[cm][p * 3 + q], sW21[cm][(ei + 2) * 5 + (ej + 2)]);
                        acc.x += t.x; acc.y += t.y;
                    }
                }
        ((float2*)kc)[(b * 2 + chain) * 49 + idx] = acc;
    }
}

// main composed 7x7 conv. block 16x16, per-thread 8-row column sweep
// (128x16 output tile, halo 3).
// MODE 0 (fwd): input = rh quadrant (antisym mirror read, real), out fp32.
// MODE 1 (adj): input = (or,oi)*wt*ik2 (fused k_scale), out bf16 dA3 planes
//               laid out [row][k] with real at k<513, imag at 513..1025.
template <int MODE>
__global__ __launch_bounds__(256) void k_conv7(
    const float* __restrict__ xr, const float* __restrict__ xi,
    const float* __restrict__ wtr, const float* __restrict__ wti,
    const float* __restrict__ kc,
    float* __restrict__ outr, float* __restrict__ outi,
    ushort* __restrict__ oAh, ushort* __restrict__ oAl) {
    constexpr bool CPLX = (MODE == 1);
    __shared__ float2 tile[134][23];
    __shared__ float2 kt[49];
    int b = blockIdx.z;
    int tid = threadIdx.y * 16 + threadIdx.x;
    const float2* kb = (const float2*)kc + (b * 2 + MODE) * 49;
    for (int idx = tid; idx < 49; idx += 256) kt[idx] = kb[idx];
    int row_base = blockIdx.y * 128 - 3;
    int col_base = blockIdx.x * 16 - 3;
    const float* rq = xr + (long long)b * NQ;
    for (int idx = tid; idx < 134 * 22; idx += 256) {
        int r = idx / 22, c = idx % 22;
        int gr = row_base + r, gc = col_base + c;
        float vr = 0.0f, vi = 0.0f;
        if (gr >= 0 && gr < NGRID && gc >= 0 && gc < NGRID) {
            if (MODE == 0) {
                vr = rhq_read(rq, gr, gc);
            } else {
                long long g = (long long)b * N2G + (long long)gr * NGRID + gc;
                float2 sc = scale_wt(xr[g], xi[g], wtr[g], wti[g], gr, gc);
                vr = sc.x; vi = sc.y;
            }
        }
        tile[r][c] = make_float2(vr, vi);
    }
    __syncthreads();

    int tx = threadIdx.x, r0 = threadIdx.y * 8;
    float2 acc[8];
    #pragma unroll
    for (int r = 0; r < 8; ++r) acc[r] = make_float2(0.f, 0.f);
    #pragma unroll
    for (int t = 0; t < 7; ++t) {
        float2 kv[7];
        #pragma unroll
        for (int s = 0; s < 7; ++s) kv[s] = kt[s * 7 + t];
        #pragma unroll
        for (int rr = 0; rr < 14; ++rr) {
            float2 xv = tile[r0 + rr][tx + t];
            #pragma unroll
            for (int s = 0; s < 7; ++s) {
                int orow = rr - s;
                if (orow >= 0 && orow < 8) {
                    acc[orow].x += kv[s].x * xv.x;
                    acc[orow].y += kv[s].y * xv.x;
                    if (CPLX) {
                        acc[orow].x -= kv[s].y * xv.y;
                        acc[orow].y += kv[s].x * xv.y;
                    }
                }
            }
        }
    }
    int gc = blockIdx.x * 16 + tx;
    if (gc >= NGRID) return;
    #pragma unroll
    for (int r = 0; r < 8; ++r) {
        int gr = blockIdx.y * 128 + r0 + r;
        if (gr < NGRID) {
            if (MODE == 0) {
                long long g = (long long)b * N2G + (long long)gr * NGRID + gc;
                outr[g] = acc[r].x;
                outi[g] = acc[r].y;
            } else {
                long long o = (long long)b * 513 * 1056
                            + (long long)gr * 1056 + gc;
                ushort h = f2bf(acc[r].x);
                oAh[o] = h;
                oAl[o] = f2bf(acc[r].x - bf2f(h));
                ushort h2 = f2bf(acc[r].y);
                oAh[o + 513] = h2;
                oAl[o + 513] = f2bf(acc[r].y - bf2f(h2));
            }
        }
    }
}

// exact sequential recompute of the width-2 border ring (same input/output
// conventions as k_conv7<CHAIN>). sides: 0 top, 1 bottom, 2 left, 3 right.
template <int CHAIN>
__global__ __launch_bounds__(256) void k_ring7(
    const float* __restrict__ xr, const float* __restrict__ xi,
    const float* __restrict__ wtr, const float* __restrict__ wti,
    const float* __restrict__ w1r, const float* __restrict__ w1i,
    const float* __restrict__ w2r, const float* __restrict__ w2i,
    const float* __restrict__ w3r, const float* __restrict__ w3i,
    float* __restrict__ outr, float* __restrict__ outi,
    ushort* __restrict__ oAh, ushort* __restrict__ oAl) {
    constexpr bool CPLX = (CHAIN == 1);
    __shared__ float2 W1s[4][9], W2s[16][9], W3s[4][9];
    __shared__ float2 Y[4][4][68];
    __shared__ float2 Z[4][3][66];
    int side = blockIdx.y, b = blockIdx.z;
    int u0 = blockIdx.x * 64;
    int ulo = (side < 2) ? 0 : 2;
    int uhi = (side < 2) ? (NGRID - 1) : (NGRID - 3);
    if (u0 > uhi) return;
    int tid = threadIdx.x;
    const float* rq = xr + (long long)b * NQ;

    for (int idx = tid; idx < 36; idx += 256) {
        int c = idx / 9, s = idx % 9, p = s / 3, q = s % 3;
        if (CHAIN == 0) {
            int i1 = b * 36 + c * 9 + p * 3 + q;
            W1s[c][s] = make_float2(w1r[i1], w1i[i1]);
            W3s[c][s] = make_float2(w3r[i1], w3i[i1]);
        } else {
            int it = b * 36 + c * 9 + q * 3 + p;
            W1s[c][s] = make_float2(w3r[it], -w3i[it]);
            W3s[c][s] = make_float2(w1r[it], -w1i[it]);
        }
    }
    for (int idx = tid; idx < 144; idx += 256) {
        int co = idx / 36, r = idx % 36, ci = r / 9, s = r % 9, p = s / 3, q = s % 3;
        int iw = (CHAIN == 0) ? (b * 144 + co * 36 + ci * 9 + p * 3 + q)
                              : (b * 144 + ci * 36 + co * 9 + q * 3 + p);
        float iv = w2i[iw];
        W2s[co * 4 + ci][s] = make_float2(w2r[iw], (CHAIN == 0) ? iv : -iv);
    }
    __syncthreads();

    // stage 1: y = conv1(x) on band d 0..3, u in [u0-2, u0+65]
    for (int idx = tid; idx < 4 * 4 * 68; idx += 256) {
        int ch = idx / (4 * 68), r = idx % (4 * 68), d = r / 68, uu = r % 68;
        int u = u0 - 2 + uu;
        float2 acc = make_float2(0.f, 0.f);
        if (u >= 0 && u < NGRID) {
            int i, j;
            if (side == 0)      { i = d;       j = u; }
            else if (side == 1) { i = 512 - d; j = u; }
            else if (side == 2) { i = u;       j = d; }
            else                { i = u;       j = 512 - d; }
            for (int p = 0; p < 3; ++p)
                for (int q = 0; q < 3; ++q) {
                    int ii = i + p - 1, jj = j + q - 1;
                    if (ii >= 0 && ii < NGRID && jj >= 0 && jj < NGRID) {
                        float vr, vi;
                        if (CHAIN == 0) {
                            vr = rhq_read(rq, ii, jj);
                            vi = 0.0f;
                        } else {
                            long long g = (long long)b * N2G
                                        + (long long)ii * NGRID + jj;
                            float2 sc = scale_wt(xr[g], xi[g], wtr[g], wti[g],
                                                 ii, jj);
                            vr = sc.x; vi = sc.y;
                        }
                        float2 w = W1s[ch][p * 3 + q];
                        acc.x += w.x * vr - w.y * vi;
                        acc.y += w.x * vi + w.y * vr;
                    }
                }
        }
        Y[ch][d][uu] = acc;
    }
    __syncthreads();

    // stage 2: z = conv2(y)
    for (int idx = tid; idx < 4 * 3 * 66; idx += 256) {
        int co = idx / (3 * 66), r = idx % (3 * 66), d = r / 66, uu = r % 66;
        int u = u0 - 1 + uu;
        float2 acc = make_float2(0.f, 0.f);
        if (u >= 0 && u < NGRID) {
            for (int p = 0; p < 3; ++p)
                for (int q = 0; q < 3; ++q) {
                    int dd, du;
                    if (side == 0)      { dd = p - 1; du = q - 1; }
                    else if (side == 1) { dd = 1 - p; du = q - 1; }
                    else if (side == 2) { dd = q - 1; du = p - 1; }
                    else                { dd = 1 - q; du = p - 1; }
                    int d2 = d + dd, uy = uu + 1 + du;
                    if (d2 >= 0) {
                        for (int ci = 0; ci < 4; ++ci) {
                            float2 yv = Y[ci][d2][uy];
                            float2 w = W2s[co * 4 + ci][p * 3 + q];
                            acc.x += w.x * yv.x - w.y * yv.y;
                            acc.y += w.x * yv.y + w.y * yv.x;
                        }
                    }
                }
        }
        Z[co][d][uu] = acc;
    }
    __syncthreads();

    // stage 3: ring outputs d in {0,1}; overwrite composed values
    for (int idx = tid; idx < 128; idx += 256) {
        int d = idx / 64, uu = idx % 64;
        int u = u0 + uu;
        if (u < ulo || u > uhi) continue;
        float2 acc = make_float2(0.f, 0.f);
        for (int p = 0; p < 3; ++p)
            for (int q = 0; q < 3; ++q) {
                int dd, du;
                if (side == 0)      { dd = p - 1; du = q - 1; }
                else if (side == 1) { dd = 1 - p; du = q - 1; }
                else if (side == 2) { dd = q - 1; du = p - 1; }
                else                { dd = 1 - q; du = p - 1; }
                int d2 = d + dd, uz = uu + 1 + du;
                if (d2 >= 0) {
                    for (int ci = 0; ci < 4; ++ci) {
                        float2 zv = Z[ci][d2][uz];
                        float2 w = W3s[ci][p * 3 + q];
                        acc.x += w.x * zv.x - w.y * zv.y;
                        acc.y += w.x * zv.y + w.y * zv.x;
                    }
                }
            }
        int i, j;
        if (side == 0)      { i = d;       j = u; }
        else if (side == 1) { i = 512 - d; j = u; }
        else if (side == 2) { i = u;       j = d; }
        else                { i = u;       j = 512 - d; }
        if (CHAIN == 0) {
            long long g = (long long)b * N2G + (long long)i * NGRID + j;
            outr[g] = acc.x;
            outi[g] = acc.y;
        } else {
            long long o = (long long)b * 513 * 1056 + (long long)i * 1056 + j;
            ushort h = f2bf(acc.x);
            oAh[o] = h;
            oAl[o] = f2bf(acc.x - bf2f(h));
            ushort h2 = f2bf(acc.y);
            oAh[o + 513] = h2;
            oAl[o + 513] = f2bf(acc.y - bf2f(h2));
        }
    }
}

// per-batch: red[2b] += sum(r*e), red[2b+1] += sum(Ae*e)
__global__ void k_dot2(const float* __restrict__ r, const float* __restrict__ e,
                       const float* __restrict__ Ae, float* __restrict__ red) {
    int b = blockIdx.y;
    const float* rb = r + (long long)b * N2G;
    const float* eb = e + (long long)b * N2G;
    const float* ab = Ae + (long long)b * N2G;
    float s1 = 0.0f, s2 = 0.0f;
    for (int i = blockIdx.x * blockDim.x + threadIdx.x; i < N2G;
         i += gridDim.x * blockDim.x) {
        float ev = eb[i];
        s1 += rb[i] * ev;
        s2 += ab[i] * ev;
    }
    #pragma unroll
    for (int o = 32; o > 0; o >>= 1) {
        s1 += __shfl_down(s1, o);
        s2 += __shfl_down(s2, o);
    }
    __shared__ float l1[4], l2[4];
    int wid = threadIdx.x >> 6;
    if ((threadIdx.x & 63) == 0) { l1[wid] = s1; l2[wid] = s2; }
    __syncthreads();
    if (threadIdx.x == 0) {
        atomicAdd(&red[2 * b], l1[0] + l1[1] + l1[2] + l1[3]);
        atomicAdd(&red[2 * b + 1], l2[0] + l2[1] + l2[2] + l2[3]);
    }
}

__global__ void k_update(float* __restrict__ x, const float* __restrict__ e,
                         const float* __restrict__ red) {
    long long idx = (long long)blockIdx.x * blockDim.x + threadIdx.x;
    if (idx >= (long long)NB * N2G) return;
    int b = (int)(idx / N2G);
    float alpha = red[2 * b] / red[2 * b + 1];
    x[idx] += alpha * e[idx];
}

__global__ void k_norm(const float* __restrict__ r, const float* __restrict__ f,
                       float* __restrict__ red) {
    float s1 = 0.0f, s2 = 0.0f;
    for (long long i = (long long)blockIdx.x * blockDim.x + threadIdx.x;
         i < (long long)NB * N2G; i += (long long)gridDim.x * blockDim.x) {
        float rv = r[i], fv = f[i];
        s1 += rv * rv;
        s2 += fv * fv;
    }
    #pragma unroll
    for (int o = 32; o > 0; o >>= 1) {
        s1 += __shfl_down(s1, o);
        s2 += __shfl_down(s2, o);
    }
    __shared__ float l1[4], l2[4];
    int wid = threadIdx.x >> 6;
    if ((threadIdx.x & 63) == 0) { l1[wid] = s1; l2[wid] = s2; }
    __syncthreads();
    if (threadIdx.x == 0) {
        atomicAdd(&red[8], l1[0] + l1[1] + l1[2] + l1[3]);
        atomicAdd(&red[9], l2[0] + l2[1] + l2[2] + l2[3]);
    }
}

__global__ void k_final(const float* __restrict__ red, float* __restrict__ out) {
    out[0] = sqrtf(red[8] / red[9]);
}

// ---------------------------------------------------------------------------
extern "C" void kernel_launch(void* const* d_in, const int* in_sizes, int n_in,
                              void* d_out, int out_size, void* d_ws, size_t ws_size,
                              hipStream_t stream) {
    (void)in_sizes; (void)n_in; (void)out_size; (void)ws_size;
    const float* f    = (const float*)d_in[0];
    const float* coef = (const float*)d_in[1];
    const float* w1r  = (const float*)d_in[3];
    const float* w1i  = (const float*)d_in[4];
    const float* w2r  = (const float*)d_in[5];
    const float* w2i  = (const float*)d_in[6];
    const float* w3r  = (const float*)d_in[7];
    const float* w3i  = (const float*)d_in[8];
    const float* wtr  = (const float*)d_in[9];
    const float* wti  = (const float*)d_in[10];
    float* out = (float*)d_out;

    float* ws = (float*)d_ws;
    size_t off = 0;
    auto alloc = [&](long long n) {
        float* p = ws + off;
        off += (size_t)((n + 3) & ~3LL);
        return p;
    };
    float* x0   = alloc((long long)NB * N2G);
    float* x1   = alloc((long long)NB * N2G);
    float* rr   = alloc((long long)NB * N2G);
    float* ee   = alloc((long long)NB * N2G);
    float* dinv = alloc((long long)NB * NI2);
    float* c1r  = alloc((long long)NB * 4 * N2G);
    float* c1i  = alloc((long long)NB * 4 * N2G);
    float* c2r  = alloc((long long)NB * 4 * N2G);
    float* c2i  = alloc((long long)NB * 4 * N2G);
    float* pr   = c1r;  // partial span (c1r..c2i contiguous, ~67 MB)
    float* or_  = alloc((long long)NB * N2G);
    float* oi_  = alloc((long long)NB * N2G);
    float* rhq  = alloc((long long)NB * NQ);   // rh antisym quadrant 257x257
    float* red  = alloc(16);
    ushort* sGh  = (ushort*)alloc(513 * 512 / 2);
    ushort* sGl  = (ushort*)alloc(513 * 512 / 2);
    ushort* sGth = (ushort*)alloc(513 * 512 / 2);
    ushort* sGtl = (ushort*)alloc(513 * 512 / 2);
    ushort* sFAh = (ushort*)alloc(511 * 1056 / 2);
    ushort* sFAl = (ushort*)alloc(511 * 1056 / 2);
    ushort* sFBh = (ushort*)alloc(1022 * 1056 / 2);
    ushort* sFBl = (ushort*)alloc(1022 * 1056 / 2);
    // disjoint bf16 operand buffers (pads zeroed once per launch):
    ushort* dA2h = (ushort*)alloc((long long)NB * 257 * 512 / 2);  // gemm2 A
    ushort* dA2l = (ushort*)alloc((long long)NB * 257 * 512 / 2);
    ushort* dA3h = (ushort*)alloc((long long)NB * 513 * 1056 / 2); // gemm3 B
    ushort* dA3l = (ushort*)alloc((long long)NB * 513 * 1056 / 2);
    ushort* dB1h = (ushort*)alloc((long long)NB * 511 * 512 / 2);  // gemm1 B
    ushort* dB1l = (ushort*)alloc((long long)NB * 511 * 512 / 2);
    ushort* dB4h = (ushort*)alloc((long long)NB * 511 * 1056 / 2); // gemm4 B
    ushort* dB4l = (ushort*)alloc((long long)NB * 511 * 1056 / 2);
    float* kcomp = alloc(NB * 2 * 49 * 2);   // composed 7x7 chain kernels
    float* Ae   = or_;  // or_ dead after the adjoint conv reads it

    dim3 blk2(16, 16);
    dim3 grdS(33, 33, NB);
    dim3 grdC(33, 5, NB);    // conv7: 16x128 output tile per block
    dim3 grdR(9, 4, NB);     // ring7: 64-wide segments x 4 sides
    const int SP = 4;        // split-K (validated R15)

    hipMemsetAsync(x0, 0, (size_t)NB * N2G * sizeof(float), stream);
    // zero bf16 buffers whose pad regions are never rewritten in-loop
    // (dA3h/dA3l adjacent; dB1h/dB1l adjacent — allocator keeps 4-float align)
    hipMemsetAsync(dA3h, 0, (size_t)NB * 513 * 1056 * 2 * 2, stream);
    hipMemsetAsync(dB1h, 0, (size_t)NB * 511 * 512 * 2 * 2, stream);
    k_dinv<<<dim3((NB * NI2 + 255) / 256), dim3(256), 0, stream>>>(coef, dinv);
    k_genDSTA<<<dim3((513 * 512 + 255) / 256), dim3(256), 0, stream>>>(sGh, sGl);
    k_genDSTB<<<dim3((513 * 512 + 255) / 256), dim3(256), 0, stream>>>(sGth, sGtl);
    k_genFA<<<dim3((511 * 1056 + 255) / 256), dim3(256), 0, stream>>>(sFAh, sFAl);
    k_genFB<<<dim3((1022 * 1056 + 255) / 256), dim3(256), 0, stream>>>(sFBh, sFBl);
    k_compose<<<dim3(2, NB), dim3(128), 0, stream>>>(w1r, w1i, w2r, w2i, w3r, w3i, kcomp);

    float* xa = x0;
    float* xb = x1;
    for (int step = 0; step < 2; ++step) {
        // 10 weighted-Jacobi sweeps as 2 fused 5-sweep launches
        for (int it = 0; it < 2; ++it) {
            k_jacobi5<<<grdS, blk2, 0, stream>>>(xa, coef, f, dinv, xb);
            float* t = xa; xa = xb; xb = t;
        }
        // residual + fused bf16 transpose planes for gemm1 B
        k_stencil<<<grdS, blk2, 0, stream>>>(xa, coef, f, rr, 0, dB1h, dB1l);

        // ---- H_apply ----
        // gemm1: t2 = G(257x511) * rI(511x511)   [antisym: M 513 -> 257]
        k_mgemm<<<dim3(4, 3, NB * SP), dim3(256), 0, stream>>>(
            sGh, sGl, 0, dB1h, dB1l, (long long)511 * 512,
            pr, (long long)257 * 511, 257, 511, 512, SP);
        k_redA<<<dim3((257 * 512 + 255) / 256, NB), dim3(256), 0, stream>>>(
            pr, SP, 257, dA2h, dA2l);
        // gemm2: rh_q = t2(257x511) * Gt(511x257) [antisym: N 513 -> 257]
        k_mgemm<<<dim3(3, 3, NB * SP), dim3(256), 0, stream>>>(
            dA2h, dA2l, (long long)257 * 512, sGth, sGtl, 0,
            pr, (long long)NQ, 257, 257, 512, SP);
        k_reduce<<<dim3(259, NB), dim3(256), 0, stream>>>(
            pr, rhq, NQ, 257, 257, (long long)NQ, SP);

        // forward conv chain (rh mirror-read) -> or_/oi_
        k_conv7<0><<<grdC, blk2, 0, stream>>>(
            rhq, nullptr, nullptr, nullptr, kcomp, or_, oi_, nullptr, nullptr);
        k_ring7<0><<<grdR, dim3(256), 0, stream>>>(
            rhq, nullptr, nullptr, nullptr,
            w1r, w1i, w2r, w2i, w3r, w3i, or_, oi_, nullptr, nullptr);
        // adjoint conv chain (fused wt*ik2 scale on load) -> bf16 dA3 planes
        k_conv7<1><<<grdC, blk2, 0, stream>>>(
            or_, oi_, wtr, wti, kcomp, nullptr, nullptr, dA3h, dA3l);
        k_ring7<1><<<grdR, dim3(256), 0, stream>>>(
            or_, oi_, wtr, wti,
            w1r, w1i, w2r, w2i, w3r, w3i, nullptr, nullptr, dA3h, dA3l);

        // gemm3' (transposed): P'[n<1022][m<513] = sFB * dA3^T
        k_mgemm<<<dim3(5, 8, NB * 4), dim3(256), 0, stream>>>(
            sFBh, sFBl, 0, dA3h, dA3l, (long long)513 * 1056,
            pr, 1022LL * 513, 1022, 513, 1056, 4);
        k_redBt<<<dim3(2109, NB), dim3(256), 0, stream>>>(pr, 4, dB4h, dB4l);
        // gemm4: e = [Fr|Fi](511x1026) * [t2r;-t2i](1026x511)
        k_mgemm<<<dim3(4, 4, NB * SP), dim3(256), 0, stream>>>(
            sFAh, sFAl, 0, dB4h, dB4l, (long long)511 * 1056,
            pr, (long long)NI2, 511, 511, 1056, SP);
        hipMemsetAsync(ee, 0, (size_t)NB * N2G * sizeof(float), stream);
        k_reduce<<<dim3(1024, NB), dim3(256), 0, stream>>>(
            pr, ee + NGRID + 1, NI2, NINT, NGRID, (long long)N2G, SP);

        // Ae = A e ; alpha = (r.e)/(Ae.e) ; x += alpha e
        k_stencil<<<grdS, blk2, 0, stream>>>(ee, coef, nullptr, Ae, 2,
                                             nullptr, nullptr);
        hipMemsetAsync(red, 0, 8 * sizeof(float), stream);
        k_dot2<<<dim3(64, NB), dim3(256), 0, stream>>>(rr, ee, Ae, red);
        k_update<<<dim3((NB * N2G + 255) / 256), dim3(256), 0, stream>>>(xa, ee, red);
    }
    k_stencil<<<grdS, blk2, 0, stream>>>(xa, coef, f, rr, 0, nullptr, nullptr);
    hipMemsetAsync(red + 8, 0, 2 * sizeof(float), stream);
    k_norm<<<dim3(256), dim3(256), 0, stream>>>(rr, f, red);
    k_final<<<dim3(1), dim3(1), 0, stream>>>(red, out);
}

// Round 3
// 683.108 us; speedup vs baseline: 1.2764x; 1.0555x over previous
//
#include <hip/hip_runtime.h>
#include <math.h>

#ifndef M_PI
#define M_PI 3.14159265358979323846
#endif

#define NGRID 513
#define NCELL 512
#define NINT  511
#define NB    4

constexpr int N2G = NGRID * NGRID;   // 263169
constexpr int NI2 = NINT * NINT;     // 261121
constexpr int NQ  = 257 * 257;       // 66049 (rh antisym quadrant)

typedef unsigned short ushort;
typedef unsigned int uint32;
typedef __attribute__((ext_vector_type(8))) short short8;
typedef __attribute__((ext_vector_type(8))) unsigned short ushort8;
typedef __attribute__((ext_vector_type(4))) float f32x4;

// ---------------------------------------------------------------------------
// bf16 split helpers (RNE)
// ---------------------------------------------------------------------------
__device__ __forceinline__ ushort f2bf(float x) {
    unsigned u = __float_as_uint(x);
    unsigned r = u + 0x7FFFu + ((u >> 16) & 1u);
    return (ushort)(r >> 16);
}
__device__ __forceinline__ float bf2f(ushort h) {
    return __uint_as_float(((unsigned)h) << 16);
}

// rh antisymmetric-quadrant read: rq = batch base (257x257), (i,j) full-grid.
// rh[256+d] = -rh[256-d] exactly (DST row negation is IEEE-exact).
__device__ __forceinline__ float rhq_read(const float* __restrict__ rq,
                                          int i, int j) {
    float s = 1.0f;
    if (i > 256) { i = 512 - i; s = -s; }
    if (j > 256) { j = 512 - j; s = -s; }
    return s * rq[i * 257 + j];
}

// wt * ik2 complex scale (bitwise-identical to the old k_scale expression)
__device__ __forceinline__ float2 scale_wt(float x0, float x1, float wr, float wi,
                                           int gr, int gc) {
    int du = gr - 256, dv = gc - 256;
    float ik2;
    if (du == 0 && dv == 0)
        ik2 = 1.0f;
    else
        ik2 = (float)(1.0 / (9.869604401089358 * (double)(du * du + dv * dv)));
    return make_float2((x0 * wr - x1 * wi) * ik2, (x0 * wi + x1 * wr) * ik2);
}

// ---------------------------------------------------------------------------
// FEM Darcy operator at interior node (i,j), i,j in 1..511
// ---------------------------------------------------------------------------
__device__ __forceinline__ float darcyA(const float* __restrict__ x,
                                        const float* __restrict__ a,
                                        int i, int j) {
    const float c23 = 2.0f / 3.0f, c16 = 1.0f / 6.0f, c13 = 1.0f / 3.0f;
    float a00 = a[(i - 1) * NCELL + (j - 1)];
    float a01 = a[(i - 1) * NCELL + j];
    float a10 = a[i * NCELL + (j - 1)];
    float a11 = a[i * NCELL + j];
    const float* xm = x + (i - 1) * NGRID;
    const float* xc = x + i * NGRID;
    const float* xp = x + (i + 1) * NGRID;
    return c23 * (a00 + a01 + a10 + a11) * xc[j]
         - c16 * ((a00 + a01) * xm[j] + (a10 + a11) * xp[j]
                + (a00 + a10) * xc[j - 1] + (a01 + a11) * xc[j + 1])
         - c13 * (a00 * xm[j - 1] + a01 * xm[j + 1]
                + a10 * xp[j - 1] + a11 * xp[j + 1]);
}

// mode 0: out = f - A x (+ optional fused bf16 transpose planes for gemm1 B)
// mode 2: out = A x (interior), 0 boundary
__global__ void k_stencil(const float* __restrict__ xin,
                          const float* __restrict__ a,
                          const float* __restrict__ f,
                          float* __restrict__ out, int mode,
                          ushort* __restrict__ tBh, ushort* __restrict__ tBl) {
    __shared__ float st[16][17];
    int b = blockIdx.z;
    int j = blockIdx.x * 16 + threadIdx.x;
    int i = blockIdx.y * 16 + threadIdx.y;
    const float* xb = xin + (long long)b * N2G;
    const float* ab = a + (long long)b * NCELL * NCELL;
    bool ingrid = (i < NGRID && j < NGRID);
    bool interior = ingrid && i >= 1 && i <= NINT && j >= 1 && j <= NINT;
    float v = 0.0f;
    long long idx = (long long)b * N2G + (long long)i * NGRID + j;
    if (interior) {
        float Ax = darcyA(xb, ab, i, j);
        v = (mode == 0) ? f[idx] - Ax : Ax;
    } else if (ingrid) {
        v = (mode == 0) ? f[idx] : 0.0f;
    }
    if (ingrid) out[idx] = v;
    if (mode == 0 && tBh) {
        st[threadIdx.y][threadIdx.x] = v;
        __syncthreads();
        int tx = threadIdx.x, ty = threadIdx.y;
        int i2 = blockIdx.y * 16 + tx;   // = k+1
        int j2 = blockIdx.x * 16 + ty;   // = n+1
        if (i2 >= 1 && i2 <= NINT && j2 >= 1 && j2 <= NINT) {
            float rv = st[tx][ty];
            ushort h = f2bf(rv);
            long long o = (long long)b * 511 * 512
                        + (long long)(j2 - 1) * 512 + (i2 - 1);
            tBh[o] = h;
            tBl[o] = f2bf(rv - bf2f(h));
        }
    }
}

// ---------------------------------------------------------------------------
// 5 fused weighted-Jacobi sweeps per launch (halo 5, LDS ping-pong stages).
// ---------------------------------------------------------------------------
__global__ void k_jacobi5(const float* __restrict__ xin,
                          const float* __restrict__ a,
                          const float* __restrict__ f,
                          const float* __restrict__ dinv,
                          float* __restrict__ out) {
    __shared__ float sx[26][26];
    __shared__ float sa[25][26];
    __shared__ float sf[24][24];
    __shared__ float sd[24][24];
    __shared__ float sp[2][24][26];
    const float c23 = 2.0f / 3.0f, c16 = 1.0f / 6.0f, c13 = 1.0f / 3.0f;
    int b = blockIdx.z;
    const float* xb = xin + (long long)b * N2G;
    const float* ab = a + (long long)b * NCELL * NCELL;
    const float* fb = f + (long long)b * N2G;
    const float* db = dinv + (long long)b * NI2;
    int ox = blockIdx.x * 16, oy = blockIdx.y * 16;
    int tx = threadIdx.x, ty = threadIdx.y;
    int tid = ty * 16 + tx;

    for (int idx = tid; idx < 26 * 26; idx += 256) {
        int ly = idx / 26, lx = idx % 26;
        int gy = oy - 5 + ly, gx = ox - 5 + lx;
        bool in = (gy >= 0 && gy < NGRID && gx >= 0 && gx < NGRID);
        sx[ly][lx] = in ? xb[(long long)gy * NGRID + gx] : 0.0f;
    }
    for (int idx = tid; idx < 25 * 25; idx += 256) {
        int ly = idx / 25, lx = idx % 25;
        int gy = oy - 5 + ly, gx = ox - 5 + lx;
        bool in = (gy >= 0 && gy < NCELL && gx >= 0 && gx < NCELL);
        sa[ly][lx] = in ? ab[(long long)gy * NCELL + gx] : 0.0f;
    }
    for (int idx = tid; idx < 24 * 24; idx += 256) {
        int ly = idx / 24, lx = idx % 24;
        int gy = oy - 4 + ly, gx = ox - 4 + lx;
        bool ing = (gy >= 0 && gy < NGRID && gx >= 0 && gx < NGRID);
        bool itr = (gy >= 1 && gy <= NINT && gx >= 1 && gx <= NINT);
        sf[ly][lx] = ing ? fb[(long long)gy * NGRID + gx] : 0.0f;
        sd[ly][lx] = itr ? db[(long long)(gy - 1) * NINT + (gx - 1)] : 0.0f;
    }
    __syncthreads();

    for (int idx = tid; idx < 24 * 24; idx += 256) {
        int ly = idx / 24, lx = idx % 24;
        int gy = oy - 4 + ly, gx = ox - 4 + lx;
        float v = 0.0f;
        if (gy >= 0 && gy < NGRID && gx >= 0 && gx < NGRID) {
            float xc = sx[ly + 1][lx + 1];
            if (gy >= 1 && gy <= NINT && gx >= 1 && gx <= NINT) {
                float a00 = sa[ly][lx], a01 = sa[ly][lx + 1];
                float a10 = sa[ly + 1][lx], a11 = sa[ly + 1][lx + 1];
                float Ax = c23 * (a00 + a01 + a10 + a11) * xc
                    - c16 * ((a00 + a01) * sx[ly][lx + 1] + (a10 + a11) * sx[ly + 2][lx + 1]
                           + (a00 + a10) * sx[ly + 1][lx] + (a01 + a11) * sx[ly + 1][lx + 2])
                    - c13 * (a00 * sx[ly][lx] + a01 * sx[ly][lx + 2]
                           + a10 * sx[ly + 2][lx] + a11 * sx[ly + 2][lx + 2]);
                v = xc + 0.75f * sd[ly][lx] * (sf[ly][lx] - Ax);
            } else {
                v = xc;
            }
        }
        sp[0][ly][lx] = v;
    }
    __syncthreads();

    #pragma unroll 1
    for (int s = 2; s <= 4; ++s) {
        int sz = 24 - 2 * (s - 1);
        int cur = (s - 1) & 1, prv = s & 1;
        for (int idx = tid; idx < sz * sz; idx += 256) {
            int ly = idx / sz, lx = idx % sz;
            int gy = oy - (5 - s) + ly, gx = ox - (5 - s) + lx;
            float v = 0.0f;
            if (gy >= 0 && gy < NGRID && gx >= 0 && gx < NGRID) {
                float xc = sp[prv][ly + 1][lx + 1];
                if (gy >= 1 && gy <= NINT && gx >= 1 && gx <= NINT) {
                    int ar = ly + s - 1, ac = lx + s - 1;
                    float a00 = sa[ar][ac], a01 = sa[ar][ac + 1];
                    float a10 = sa[ar + 1][ac], a11 = sa[ar + 1][ac + 1];
                    float Ax = c23 * (a00 + a01 + a10 + a11) * xc
                        - c16 * ((a00 + a01) * sp[prv][ly][lx + 1] + (a10 + a11) * sp[prv][ly + 2][lx + 1]
                               + (a00 + a10) * sp[prv][ly + 1][lx] + (a01 + a11) * sp[prv][ly + 1][lx + 2])
                        - c13 * (a00 * sp[prv][ly][lx] + a01 * sp[prv][ly][lx + 2]
                               + a10 * sp[prv][ly + 2][lx] + a11 * sp[prv][ly + 2][lx + 2]);
                    int fr = ly + s - 1, fc = lx + s - 1;
                    v = xc + 0.75f * sd[fr][fc] * (sf[fr][fc] - Ax);
                } else {
                    v = xc;
                }
            }
            sp[cur][ly][lx] = v;
        }
        __syncthreads();
    }

    {
        int gy = oy + ty, gx = ox + tx;
        if (gy < NGRID && gx < NGRID) {
            float v;
            float xc = sp[1][ty + 1][tx + 1];
            if (gy >= 1 && gy <= NINT && gx >= 1 && gx <= NINT) {
                int ar = ty + 4, ac = tx + 4;
                float a00 = sa[ar][ac], a01 = sa[ar][ac + 1];
                float a10 = sa[ar + 1][ac], a11 = sa[ar + 1][ac + 1];
                float Ax = c23 * (a00 + a01 + a10 + a11) * xc
                    - c16 * ((a00 + a01) * sp[1][ty][tx + 1] + (a10 + a11) * sp[1][ty + 2][tx + 1]
                           + (a00 + a10) * sp[1][ty + 1][tx] + (a01 + a11) * sp[1][ty + 1][tx + 2])
                    - c13 * (a00 * sp[1][ty][tx] + a01 * sp[1][ty][tx + 2]
                           + a10 * sp[1][ty + 2][tx] + a11 * sp[1][ty + 2][tx + 2]);
                v = xc + 0.75f * sd[ty + 4][tx + 4] * (sf[ty + 4][tx + 4] - Ax);
            } else {
                v = xc;
            }
            out[(long long)b * N2G + (long long)gy * NGRID + gx] = v;
        }
    }
}

__global__ void k_dinv(const float* __restrict__ a, float* __restrict__ dinv) {
    long long idx = (long long)blockIdx.x * blockDim.x + threadIdx.x;
    if (idx >= (long long)NB * NI2) return;
    int b = (int)(idx / NI2);
    int rem = (int)(idx % NI2);
    int p = rem / NINT, q = rem % NINT;
    const float* ab = a + (long long)b * NCELL * NCELL;
    float s = ab[p * NCELL + q] + ab[p * NCELL + q + 1]
            + ab[(p + 1) * NCELL + q] + ab[(p + 1) * NCELL + q + 1];
    dinv[idx] = 1.0f / ((2.0f / 3.0f) * s);
}

// ---------------------------------------------------------------------------
// Static bf16 matrix generation (hi/lo planes, K-padded, integer arg reduce)
// ---------------------------------------------------------------------------
__device__ __forceinline__ void wsplit(double v, ushort* Dh, ushort* Dl, int idx) {
    float vf = (float)v;
    ushort h = f2bf(vf);
    Dh[idx] = h;
    Dl[idx] = f2bf(vf - bf2f(h));
}

__global__ void k_genDSTA(ushort* __restrict__ Dh, ushort* __restrict__ Dl) {
    int idx = blockIdx.x * 256 + threadIdx.x;
    if (idx >= 513 * 512) return;
    int u = idx / 512, k = idx % 512;
    double v = 0.0;
    if (k < 511) {
        int t = ((u - 256) * (k + 1)) % 1024;
        if (t < 0) t += 1024;
        v = sin((M_PI / 512.0) * (double)t);
    }
    wsplit(v, Dh, Dl, idx);
}

__global__ void k_genDSTB(ushort* __restrict__ Dh, ushort* __restrict__ Dl) {
    int idx = blockIdx.x * 256 + threadIdx.x;
    if (idx >= 513 * 512) return;
    int v = idx / 512, k = idx % 512;
    double val = 0.0;
    if (k < 511) {
        int t = ((v - 256) * (k + 1)) % 1024;
        if (t < 0) t += 1024;
        val = sin((M_PI / 512.0) * (double)t) * (-1.0 / 262144.0);
    }
    wsplit(val, Dh, Dl, idx);
}

__global__ void k_genFA(ushort* __restrict__ Dh, ushort* __restrict__ Dl) {
    int idx = blockIdx.x * 256 + threadIdx.x;
    if (idx >= 511 * 1056) return;
    int y = idx / 1056, k = idx % 1056;
    double v = 0.0;
    if (k < 1026) {
        int m = (k < 513) ? k : (k - 513);
        long t = ((long)y * (m - 255)) % 1025;
        if (t < 0) t += 1025;
        double ang = (2.0 * M_PI / 1025.0) * (double)t;
        v = (k < 513) ? cos(ang) : -sin(ang);
    }
    wsplit(v, Dh, Dl, idx);
}

__global__ void k_genFB(ushort* __restrict__ Dh, ushort* __restrict__ Dl) {
    int idx = blockIdx.x * 256 + threadIdx.x;
    if (idx >= 1022 * 1056) return;
    int n = idx / 1056, k = idx % 1056;
    double v = 0.0;
    if (k < 1026) {
        int m = (k < 513) ? k : (k - 513);
        int y = (n < 511) ? n : (n - 511);
        long t = ((long)y * (m - 255)) % 1025;
        if (t < 0) t += 1025;
        double ang = (2.0 * M_PI / 1025.0) * (double)t;
        bool ktop = (k < 513), nleft = (n < 511);
        if (ktop && nleft)        v = cos(ang);
        else if (ktop && !nleft)  v = -sin(ang);
        else if (!ktop && nleft)  v = sin(ang);
        else                      v = cos(ang);
    }
    wsplit(v, Dh, Dl, idx);
}

// ---------------------------------------------------------------------------
// Fused split-K reduce + bf16 convert (GEMM->GEMM handoffs).
// ---------------------------------------------------------------------------
__global__ void k_redA(const float* __restrict__ P, int nsplit, int Mr,
                       ushort* __restrict__ Dh, ushort* __restrict__ Dl) {
    int b = blockIdx.y;
    int idx = blockIdx.x * 256 + threadIdx.x;
    if (idx >= Mr * 512) return;
    int m = idx / 512, k = idx % 512;
    float v = 0.0f;
    if (k < 511) {
        long long base = (long long)m * 511 + k;
        long long str = (long long)Mr * 511;
        #pragma unroll 4
        for (int s = 0; s < nsplit; ++s)
            v += P[((long long)b * nsplit + s) * str + base];
    }
    long long o = (long long)b * Mr * 512 + idx;
    ushort h = f2bf(v);
    Dh[o] = h;
    Dl[o] = f2bf(v - bf2f(h));
}

__global__ void k_redBt(const float* __restrict__ P, int nsplit,
                        ushort* __restrict__ Dh, ushort* __restrict__ Dl) {
    int b = blockIdx.y;
    int idx = blockIdx.x * 256 + threadIdx.x;
    if (idx >= 511 * 1056) return;
    int n = idx / 1056, k = idx % 1056;
    float v = 0.0f;
    if (k < 1026) {
        int row = (k < 513) ? n : (511 + n);
        int col = (k < 513) ? k : (k - 513);
        long long base = (long long)row * 513 + col;
        float acc = 0.0f;
        #pragma unroll 4
        for (int s = 0; s < nsplit; ++s)
            acc += P[((long long)b * nsplit + s) * (1022LL * 513) + base];
        v = (k < 513) ? acc : -acc;
    }
    long long o = (long long)b * 511 * 1056 + idx;
    ushort h = f2bf(v);
    Dh[o] = h;
    Dl[o] = f2bf(v - bf2f(h));
}

// ---------------------------------------------------------------------------
// MFMA real GEMM, 3-term split-bf16 (hh + hl + lh), 16x16x32 bf16 MFMA.
// ---------------------------------------------------------------------------
__global__ __launch_bounds__(256) void k_mgemm(
    const ushort* __restrict__ Ah, const ushort* __restrict__ Al, long long bsA,
    const ushort* __restrict__ Bh, const ushort* __restrict__ Bl, long long bsB,
    float* __restrict__ C, long long bsC,
    int M, int N, int Kp, int nsplit) {
    __shared__ ushort sAh[128 * 40];
    __shared__ ushort sAl[128 * 40];
    __shared__ ushort sBh[128 * 40];
    __shared__ ushort sBl[128 * 40];

    int bz = blockIdx.z, b = bz / nsplit, ks = bz % nsplit;
    int kchunk = (((Kp + nsplit - 1) / nsplit) + 31) & ~31;
    int kbeg = ks * kchunk;
    int kend = min(Kp, kbeg + kchunk);

    Ah += b * bsA; Al += b * bsA;
    Bh += b * bsB; Bl += b * bsB;
    C += ((long long)b * nsplit + ks) * bsC;

    int bm = blockIdx.y * 128, bn = blockIdx.x * 128;
    int tid = threadIdx.x;
    int wave = tid >> 6, lane = tid & 63;
    int wm = (wave >> 1) * 64, wn = (wave & 1) * 64;
    int quad = lane >> 4, l16 = lane & 15;

    f32x4 zf = {0.f, 0.f, 0.f, 0.f};
    f32x4 acc[4][4];
    #pragma unroll
    for (int i = 0; i < 4; ++i)
        #pragma unroll
        for (int j = 0; j < 4; ++j) acc[i][j] = zf;

    int srow = tid >> 2;
    int sk8 = (tid & 3) * 8;

    for (int kt = kbeg; kt < kend; kt += 32) {
        #pragma unroll
        for (int h = 0; h < 2; ++h) {
            int row = srow + 64 * h;
            ushort8 vh = {0, 0, 0, 0, 0, 0, 0, 0};
            ushort8 vl = {0, 0, 0, 0, 0, 0, 0, 0};
            int gm = bm + row;
            if (gm < M) {
                vh = *(const ushort8*)(Ah + (long long)gm * Kp + kt + sk8);
                vl = *(const ushort8*)(Al + (long long)gm * Kp + kt + sk8);
            }
            *(ushort8*)(sAh + row * 40 + sk8) = vh;
            *(ushort8*)(sAl + row * 40 + sk8) = vl;
            ushort8 wh = {0, 0, 0, 0, 0, 0, 0, 0};
            ushort8 wl = {0, 0, 0, 0, 0, 0, 0, 0};
            int gn = bn + row;
            if (gn < N) {
                wh = *(const ushort8*)(Bh + (long long)gn * Kp + kt + sk8);
                wl = *(const ushort8*)(Bl + (long long)gn * Kp + kt + sk8);
            }
            *(ushort8*)(sBh + row * 40 + sk8) = wh;
            *(ushort8*)(sBl + row * 40 + sk8) = wl;
        }
        __syncthreads();

        short8 afh[4], afl[4], bfh[4], bfl[4];
        #pragma unroll
        for (int t = 0; t < 4; ++t) {
            int ar = wm + t * 16 + l16;
            afh[t] = *(const short8*)(sAh + ar * 40 + quad * 8);
            afl[t] = *(const short8*)(sAl + ar * 40 + quad * 8);
            int br = wn + t * 16 + l16;
            bfh[t] = *(const short8*)(sBh + br * 40 + quad * 8);
            bfl[t] = *(const short8*)(sBl + br * 40 + quad * 8);
        }
        #pragma unroll
        for (int mt = 0; mt < 4; ++mt)
            #pragma unroll
            for (int nt = 0; nt < 4; ++nt) {
                acc[mt][nt] = __builtin_amdgcn_mfma_f32_16x16x32_bf16(
                    afh[mt], bfh[nt], acc[mt][nt], 0, 0, 0);
                acc[mt][nt] = __builtin_amdgcn_mfma_f32_16x16x32_bf16(
                    afh[mt], bfl[nt], acc[mt][nt], 0, 0, 0);
                acc[mt][nt] = __builtin_amdgcn_mfma_f32_16x16x32_bf16(
                    afl[mt], bfh[nt], acc[mt][nt], 0, 0, 0);
            }
        __syncthreads();
    }

    #pragma unroll
    for (int mt = 0; mt < 4; ++mt) {
        #pragma unroll
        for (int r = 0; r < 4; ++r) {
            int gm = bm + wm + mt * 16 + quad * 4 + r;
            if (gm >= M) continue;
            long long rowoff = (long long)gm * N;
            #pragma unroll
            for (int nt = 0; nt < 4; ++nt) {
                int gn = bn + wn + nt * 16 + l16;
                if (gn < N) C[rowoff + gn] = acc[mt][nt][r];
            }
        }
    }
}

// ---------------------------------------------------------------------------
// Sum nsplit dense [M x N] partials -> strided fp32 output (row stride ldo).
// ---------------------------------------------------------------------------
__global__ void k_reduce(const float* __restrict__ Pr,
                         float* __restrict__ outR,
                         int MN, int N, int ldo, long long bsOut, int nsplit) {
    int b = blockIdx.y;
    for (int idx = blockIdx.x * 256 + threadIdx.x; idx < MN;
         idx += gridDim.x * 256) {
        float sr = 0.0f;
        #pragma unroll 4
        for (int s = 0; s < nsplit; ++s)
            sr += Pr[((long long)b * nsplit + s) * MN + idx];
        int m = idx / N, n = idx - m * N;
        outR[(long long)b * bsOut + (long long)m * ldo + n] = sr;
    }
}

// ---------------------------------------------------------------------------
// Composed conv-chain (validated R17): each 3-conv chain == one complex 7x7.
// ---------------------------------------------------------------------------
__device__ __forceinline__ float2 cmul(float2 a, float2 b) {
    return make_float2(a.x * b.x - a.y * b.y, a.x * b.y + a.y * b.x);
}

// composed 7x7 kernels: kc[(b*2+chain)*49 + (di+3)*7 + (dj+3)] (float2)
__global__ void k_compose(const float* __restrict__ w1r, const float* __restrict__ w1i,
                          const float* __restrict__ w2r, const float* __restrict__ w2i,
                          const float* __restrict__ w3r, const float* __restrict__ w3i,
                          float* __restrict__ kc) {
    int chain = blockIdx.x, b = blockIdx.y;
    int tid = threadIdx.x;  // 128
    __shared__ float2 sW1[4][9], sW2[16][9], sW3[4][9], sW21[4][25];
    for (int idx = tid; idx < 36; idx += 128) {
        int c = idx / 9, s = idx % 9, p = s / 3, q = s % 3;
        if (chain == 0) {
            int i1 = b * 36 + c * 9 + p * 3 + q;
            sW1[c][s] = make_float2(w1r[i1], w1i[i1]);
            sW3[c][s] = make_float2(w3r[i1], w3i[i1]);
        } else {
            int it = b * 36 + c * 9 + q * 3 + p;
            sW1[c][s] = make_float2(w3r[it], -w3i[it]);
            sW3[c][s] = make_float2(w1r[it], -w1i[it]);
        }
    }
    for (int idx = tid; idx < 144; idx += 128) {
        int co = idx / 36, r = idx % 36, ci = r / 9, s = r % 9, p = s / 3, q = s % 3;
        int iw = (chain == 0) ? (b * 144 + co * 36 + ci * 9 + p * 3 + q)
                              : (b * 144 + ci * 36 + co * 9 + q * 3 + p);
        float iv = w2i[iw];
        sW2[co * 4 + ci][s] = make_float2(w2r[iw], (chain == 0) ? iv : -iv);
    }
    __syncthreads();
    for (int idx = tid; idx < 100; idx += 128) {
        int cm = idx / 25, r = idx % 25, di = r / 5 - 2, dj = r % 5 - 2;
        float2 acc = make_float2(0.f, 0.f);
        for (int c1 = 0; c1 < 4; ++c1)
            for (int p = 0; p < 3; ++p)
                for (int q = 0; q < 3; ++q) {
                    int ei = di - (p - 1) + 1, ej = dj - (q - 1) + 1;
                    if (ei >= 0 && ei < 3 && ej >= 0 && ej < 3) {
                        float2 t = cmul(sW2[cm * 4 + c1][p * 3 + q], sW1[c1][ei * 3 + ej]);
                        acc.x += t.x; acc.y += t.y;
                    }
                }
        sW21[cm][r] = acc;
    }
    __syncthreads();
    for (int idx = tid; idx < 49; idx += 128) {
        int di = idx / 7 - 3, dj = idx % 7 - 3;
        float2 acc = make_float2(0.f, 0.f);
        for (int cm = 0; cm < 4; ++cm)
            for (int p = 0; p < 3; ++p)
                for (int q = 0; q < 3; ++q) {
                    int ei = di - (p - 1), ej = dj - (q - 1);
                    if (ei >= -2 && ei <= 2 && ej >= -2 && ej <= 2) {
                        float2 t = cmul(sW3[cm][p * 3 + q], sW21[cm][(ei + 2) * 5 + (ej + 2)]);
                        acc.x += t.x; acc.y += t.y;
                    }
                }
        ((float2*)kc)[(b * 2 + chain) * 49 + idx] = acc;
    }
}

// main composed 7x7 conv. R19: occupancy re-tile — block 16x16, per-thread
// 2-row column sweep (32x16 output tile, halo 3), grid (33,17,NB)=2244
// blocks (was 660; OccupancyPercent 6.7%, VALUBusy 17% -> latency-bound).
// Same validated tap arithmetic, orow = rr - s in {0,1}.
// MODE 0 (fwd): input = rh quadrant (antisym mirror read, real), out fp32.
// MODE 1 (adj): input = (or,oi)*wt*ik2 (fused k_scale), out bf16 dA3 planes
//               laid out [row][k] with real at k<513, imag at 513..1025.
template <int MODE>
__global__ __launch_bounds__(256) void k_conv7(
    const float* __restrict__ xr, const float* __restrict__ xi,
    const float* __restrict__ wtr, const float* __restrict__ wti,
    const float* __restrict__ kc,
    float* __restrict__ outr, float* __restrict__ outi,
    ushort* __restrict__ oAh, ushort* __restrict__ oAl) {
    constexpr bool CPLX = (MODE == 1);
    __shared__ float2 tile[38][23];
    __shared__ float2 kt[49];
    int b = blockIdx.z;
    int tid = threadIdx.y * 16 + threadIdx.x;
    const float2* kb = (const float2*)kc + (b * 2 + MODE) * 49;
    for (int idx = tid; idx < 49; idx += 256) kt[idx] = kb[idx];
    int row_base = blockIdx.y * 32 - 3;
    int col_base = blockIdx.x * 16 - 3;
    const float* rq = xr + (long long)b * NQ;
    for (int idx = tid; idx < 38 * 22; idx += 256) {
        int r = idx / 22, c = idx % 22;
        int gr = row_base + r, gc = col_base + c;
        float vr = 0.0f, vi = 0.0f;
        if (gr >= 0 && gr < NGRID && gc >= 0 && gc < NGRID) {
            if (MODE == 0) {
                vr = rhq_read(rq, gr, gc);
            } else {
                long long g = (long long)b * N2G + (long long)gr * NGRID + gc;
                float2 sc = scale_wt(xr[g], xi[g], wtr[g], wti[g], gr, gc);
                vr = sc.x; vi = sc.y;
            }
        }
        tile[r][c] = make_float2(vr, vi);
    }
    __syncthreads();

    int tx = threadIdx.x, r0 = threadIdx.y * 2;
    float2 acc[2];
    acc[0] = make_float2(0.f, 0.f);
    acc[1] = make_float2(0.f, 0.f);
    #pragma unroll
    for (int t = 0; t < 7; ++t) {
        float2 kv[7];
        #pragma unroll
        for (int s = 0; s < 7; ++s) kv[s] = kt[s * 7 + t];
        #pragma unroll
        for (int rr = 0; rr < 8; ++rr) {
            float2 xv = tile[r0 + rr][tx + t];
            #pragma unroll
            for (int s = 0; s < 7; ++s) {
                int orow = rr - s;
                if (orow >= 0 && orow < 2) {
                    acc[orow].x += kv[s].x * xv.x;
                    acc[orow].y += kv[s].y * xv.x;
                    if (CPLX) {
                        acc[orow].x -= kv[s].y * xv.y;
                        acc[orow].y += kv[s].x * xv.y;
                    }
                }
            }
        }
    }
    int gc = blockIdx.x * 16 + tx;
    if (gc >= NGRID) return;
    #pragma unroll
    for (int r = 0; r < 2; ++r) {
        int gr = blockIdx.y * 32 + r0 + r;
        if (gr < NGRID) {
            if (MODE == 0) {
                long long g = (long long)b * N2G + (long long)gr * NGRID + gc;
                outr[g] = acc[r].x;
                outi[g] = acc[r].y;
            } else {
                long long o = (long long)b * 513 * 1056
                            + (long long)gr * 1056 + gc;
                ushort h = f2bf(acc[r].x);
                oAh[o] = h;
                oAl[o] = f2bf(acc[r].x - bf2f(h));
                ushort h2 = f2bf(acc[r].y);
                oAh[o + 513] = h2;
                oAl[o + 513] = f2bf(acc[r].y - bf2f(h2));
            }
        }
    }
}

// exact sequential recompute of the width-2 border ring (same input/output
// conventions as k_conv7<CHAIN>). sides: 0 top, 1 bottom, 2 left, 3 right.
template <int CHAIN>
__global__ __launch_bounds__(256) void k_ring7(
    const float* __restrict__ xr, const float* __restrict__ xi,
    const float* __restrict__ wtr, const float* __restrict__ wti,
    const float* __restrict__ w1r, const float* __restrict__ w1i,
    const float* __restrict__ w2r, const float* __restrict__ w2i,
    const float* __restrict__ w3r, const float* __restrict__ w3i,
    float* __restrict__ outr, float* __restrict__ outi,
    ushort* __restrict__ oAh, ushort* __restrict__ oAl) {
    constexpr bool CPLX = (CHAIN == 1);
    __shared__ float2 W1s[4][9], W2s[16][9], W3s[4][9];
    __shared__ float2 Y[4][4][68];
    __shared__ float2 Z[4][3][66];
    int side = blockIdx.y, b = blockIdx.z;
    int u0 = blockIdx.x * 64;
    int ulo = (side < 2) ? 0 : 2;
    int uhi = (side < 2) ? (NGRID - 1) : (NGRID - 3);
    if (u0 > uhi) return;
    int tid = threadIdx.x;
    const float* rq = xr + (long long)b * NQ;

    for (int idx = tid; idx < 36; idx += 256) {
        int c = idx / 9, s = idx % 9, p = s / 3, q = s % 3;
        if (CHAIN == 0) {
            int i1 = b * 36 + c * 9 + p * 3 + q;
            W1s[c][s] = make_float2(w1r[i1], w1i[i1]);
            W3s[c][s] = make_float2(w3r[i1], w3i[i1]);
        } else {
            int it = b * 36 + c * 9 + q * 3 + p;
            W1s[c][s] = make_float2(w3r[it], -w3i[it]);
            W3s[c][s] = make_float2(w1r[it], -w1i[it]);
        }
    }
    for (int idx = tid; idx < 144; idx += 256) {
        int co = idx / 36, r = idx % 36, ci = r / 9, s = r % 9, p = s / 3, q = s % 3;
        int iw = (CHAIN == 0) ? (b * 144 + co * 36 + ci * 9 + p * 3 + q)
                              : (b * 144 + ci * 36 + co * 9 + q * 3 + p);
        float iv = w2i[iw];
        W2s[co * 4 + ci][s] = make_float2(w2r[iw], (CHAIN == 0) ? iv : -iv);
    }
    __syncthreads();

    // stage 1: y = conv1(x) on band d 0..3, u in [u0-2, u0+65]
    for (int idx = tid; idx < 4 * 4 * 68; idx += 256) {
        int ch = idx / (4 * 68), r = idx % (4 * 68), d = r / 68, uu = r % 68;
        int u = u0 - 2 + uu;
        float2 acc = make_float2(0.f, 0.f);
        if (u >= 0 && u < NGRID) {
            int i, j;
            if (side == 0)      { i = d;       j = u; }
            else if (side == 1) { i = 512 - d; j = u; }
            else if (side == 2) { i = u;       j = d; }
            else                { i = u;       j = 512 - d; }
            for (int p = 0; p < 3; ++p)
                for (int q = 0; q < 3; ++q) {
                    int ii = i + p - 1, jj = j + q - 1;
                    if (ii >= 0 && ii < NGRID && jj >= 0 && jj < NGRID) {
                        float vr, vi;
                        if (CHAIN == 0) {
                            vr = rhq_read(rq, ii, jj);
                            vi = 0.0f;
                        } else {
                            long long g = (long long)b * N2G
                                        + (long long)ii * NGRID + jj;
                            float2 sc = scale_wt(xr[g], xi[g], wtr[g], wti[g],
                                                 ii, jj);
                            vr = sc.x; vi = sc.y;
                        }
                        float2 w = W1s[ch][p * 3 + q];
                        acc.x += w.x * vr - w.y * vi;
                        acc.y += w.x * vi + w.y * vr;
                    }
                }
        }
        Y[ch][d][uu] = acc;
    }
    __syncthreads();

    // stage 2: z = conv2(y)
    for (int idx = tid; idx < 4 * 3 * 66; idx += 256) {
        int co = idx / (3 * 66), r = idx % (3 * 66), d = r / 66, uu = r % 66;
        int u = u0 - 1 + uu;
        float2 acc = make_float2(0.f, 0.f);
        if (u >= 0 && u < NGRID) {
            for (int p = 0; p < 3; ++p)
                for (int q = 0; q < 3; ++q) {
                    int dd, du;
                    if (side == 0)      { dd = p - 1; du = q - 1; }
                    else if (side == 1) { dd = 1 - p; du = q - 1; }
                    else if (side == 2) { dd = q - 1; du = p - 1; }
                    else                { dd = 1 - q; du = p - 1; }
                    int d2 = d + dd, uy = uu + 1 + du;
                    if (d2 >= 0) {
                        for (int ci = 0; ci < 4; ++ci) {
                            float2 yv = Y[ci][d2][uy];
                            float2 w = W2s[co * 4 + ci][p * 3 + q];
                            acc.x += w.x * yv.x - w.y * yv.y;
                            acc.y += w.x * yv.y + w.y * yv.x;
                        }
                    }
                }
        }
        Z[co][d][uu] = acc;
    }
    __syncthreads();

    // stage 3: ring outputs d in {0,1}; overwrite composed values
    for (int idx = tid; idx < 128; idx += 256) {
        int d = idx / 64, uu = idx % 64;
        int u = u0 + uu;
        if (u < ulo || u > uhi) continue;
        float2 acc = make_float2(0.f, 0.f);
        for (int p = 0; p < 3; ++p)
            for (int q = 0; q < 3; ++q) {
                int dd, du;
                if (side == 0)      { dd = p - 1; du = q - 1; }
                else if (side == 1) { dd = 1 - p; du = q - 1; }
                else if (side == 2) { dd = q - 1; du = p - 1; }
                else                { dd = 1 - q; du = p - 1; }
                int d2 = d + dd, uz = uu + 1 + du;
                if (d2 >= 0) {
                    for (int ci = 0; ci < 4; ++ci) {
                        float2 zv = Z[ci][d2][uz];
                        float2 w = W3s[ci][p * 3 + q];
                        acc.x += w.x * zv.x - w.y * zv.y;
                        acc.y += w.x * zv.y + w.y * zv.x;
                    }
                }
            }
        int i, j;
        if (side == 0)      { i = d;       j = u; }
        else if (side == 1) { i = 512 - d; j = u; }
        else if (side == 2) { i = u;       j = d; }
        else                { i = u;       j = 512 - d; }
        if (CHAIN == 0) {
            long long g = (long long)b * N2G + (long long)i * NGRID + j;
            outr[g] = acc.x;
            outi[g] = acc.y;
        } else {
            long long o = (long long)b * 513 * 1056 + (long long)i * 1056 + j;
            ushort h = f2bf(acc.x);
            oAh[o] = h;
            oAl[o] = f2bf(acc.x - bf2f(h));
            ushort h2 = f2bf(acc.y);
            oAh[o + 513] = h2;
            oAl[o + 513] = f2bf(acc.y - bf2f(h2));
        }
    }
}

// per-batch: red[2b] += sum(r*e), red[2b+1] += sum(Ae*e)
__global__ void k_dot2(const float* __restrict__ r, const float* __restrict__ e,
                       const float* __restrict__ Ae, float* __restrict__ red) {
    int b = blockIdx.y;
    const float* rb = r + (long long)b * N2G;
    const float* eb = e + (long long)b * N2G;
    const float* ab = Ae + (long long)b * N2G;
    float s1 = 0.0f, s2 = 0.0f;
    for (int i = blockIdx.x * blockDim.x + threadIdx.x; i < N2G;
         i += gridDim.x * blockDim.x) {
        float ev = eb[i];
        s1 += rb[i] * ev;
        s2 += ab[i] * ev;
    }
    #pragma unroll
    for (int o = 32; o > 0; o >>= 1) {
        s1 += __shfl_down(s1, o);
        s2 += __shfl_down(s2, o);
    }
    __shared__ float l1[4], l2[4];
    int wid = threadIdx.x >> 6;
    if ((threadIdx.x & 63) == 0) { l1[wid] = s1; l2[wid] = s2; }
    __syncthreads();
    if (threadIdx.x == 0) {
        atomicAdd(&red[2 * b], l1[0] + l1[1] + l1[2] + l1[3]);
        atomicAdd(&red[2 * b + 1], l2[0] + l2[1] + l2[2] + l2[3]);
    }
}

__global__ void k_update(float* __restrict__ x, const float* __restrict__ e,
                         const float* __restrict__ red) {
    long long idx = (long long)blockIdx.x * blockDim.x + threadIdx.x;
    if (idx >= (long long)NB * N2G) return;
    int b = (int)(idx / N2G);
    float alpha = red[2 * b] / red[2 * b + 1];
    x[idx] += alpha * e[idx];
}

__global__ void k_norm(const float* __restrict__ r, const float* __restrict__ f,
                       float* __restrict__ red) {
    float s1 = 0.0f, s2 = 0.0f;
    for (long long i = (long long)blockIdx.x * blockDim.x + threadIdx.x;
         i < (long long)NB * N2G; i += (long long)gridDim.x * blockDim.x) {
        float rv = r[i], fv = f[i];
        s1 += rv * rv;
        s2 += fv * fv;
    }
    #pragma unroll
    for (int o = 32; o > 0; o >>= 1) {
        s1 += __shfl_down(s1, o);
        s2 += __shfl_down(s2, o);
    }
    __shared__ float l1[4], l2[4];
    int wid = threadIdx.x >> 6;
    if ((threadIdx.x & 63) == 0) { l1[wid] = s1; l2[wid] = s2; }
    __syncthreads();
    if (threadIdx.x == 0) {
        atomicAdd(&red[8], l1[0] + l1[1] + l1[2] + l1[3]);
        atomicAdd(&red[9], l2[0] + l2[1] + l2[2] + l2[3]);
    }
}

__global__ void k_final(const float* __restrict__ red, float* __restrict__ out) {
    out[0] = sqrtf(red[8] / red[9]);
}

// ---------------------------------------------------------------------------
extern "C" void kernel_launch(void* const* d_in, const int* in_sizes, int n_in,
                              void* d_out, int out_size, void* d_ws, size_t ws_size,
                              hipStream_t stream) {
    (void)in_sizes; (void)n_in; (void)out_size; (void)ws_size;
    const float* f    = (const float*)d_in[0];
    const float* coef = (const float*)d_in[1];
    const float* w1r  = (const float*)d_in[3];
    const float* w1i  = (const float*)d_in[4];
    const float* w2r  = (const float*)d_in[5];
    const float* w2i  = (const float*)d_in[6];
    const float* w3r  = (const float*)d_in[7];
    const float* w3i  = (const float*)d_in[8];
    const float* wtr  = (const float*)d_in[9];
    const float* wti  = (const float*)d_in[10];
    float* out = (float*)d_out;

    float* ws = (float*)d_ws;
    size_t off = 0;
    auto alloc = [&](long long n) {
        float* p = ws + off;
        off += (size_t)((n + 3) & ~3LL);
        return p;
    };
    float* x0   = alloc((long long)NB * N2G);
    float* x1   = alloc((long long)NB * N2G);
    float* rr   = alloc((long long)NB * N2G);
    float* ee   = alloc((long long)NB * N2G);
    float* dinv = alloc((long long)NB * NI2);
    float* c1r  = alloc((long long)NB * 4 * N2G);
    float* c1i  = alloc((long long)NB * 4 * N2G);
    float* c2r  = alloc((long long)NB * 4 * N2G);
    float* c2i  = alloc((long long)NB * 4 * N2G);
    float* pr   = c1r;  // partial span (c1r..c2i contiguous, ~67 MB)
    float* or_  = alloc((long long)NB * N2G);
    float* oi_  = alloc((long long)NB * N2G);
    float* rhq  = alloc((long long)NB * NQ);   // rh antisym quadrant 257x257
    float* red  = alloc(16);
    ushort* sGh  = (ushort*)alloc(513 * 512 / 2);
    ushort* sGl  = (ushort*)alloc(513 * 512 / 2);
    ushort* sGth = (ushort*)alloc(513 * 512 / 2);
    ushort* sGtl = (ushort*)alloc(513 * 512 / 2);
    ushort* sFAh = (ushort*)alloc(511 * 1056 / 2);
    ushort* sFAl = (ushort*)alloc(511 * 1056 / 2);
    ushort* sFBh = (ushort*)alloc(1022 * 1056 / 2);
    ushort* sFBl = (ushort*)alloc(1022 * 1056 / 2);
    // disjoint bf16 operand buffers (pads zeroed once per launch):
    ushort* dA2h = (ushort*)alloc((long long)NB * 257 * 512 / 2);  // gemm2 A
    ushort* dA2l = (ushort*)alloc((long long)NB * 257 * 512 / 2);
    ushort* dA3h = (ushort*)alloc((long long)NB * 513 * 1056 / 2); // gemm3 B
    ushort* dA3l = (ushort*)alloc((long long)NB * 513 * 1056 / 2);
    ushort* dB1h = (ushort*)alloc((long long)NB * 511 * 512 / 2);  // gemm1 B
    ushort* dB1l = (ushort*)alloc((long long)NB * 511 * 512 / 2);
    ushort* dB4h = (ushort*)alloc((long long)NB * 511 * 1056 / 2); // gemm4 B
    ushort* dB4l = (ushort*)alloc((long long)NB * 511 * 1056 / 2);
    float* kcomp = alloc(NB * 2 * 49 * 2);   // composed 7x7 chain kernels
    float* Ae   = or_;  // or_ dead after the adjoint conv reads it

    dim3 blk2(16, 16);
    dim3 grdS(33, 33, NB);
    dim3 grdC(33, 17, NB);   // conv7: 16x32 output tile per block (R19)
    dim3 grdR(9, 4, NB);     // ring7: 64-wide segments x 4 sides
    const int SP = 4;        // split-K (validated R15)

    hipMemsetAsync(x0, 0, (size_t)NB * N2G * sizeof(float), stream);
    // zero bf16 buffers whose pad regions are never rewritten in-loop
    hipMemsetAsync(dA3h, 0, (size_t)NB * 513 * 1056 * 2 * 2, stream);
    hipMemsetAsync(dB1h, 0, (size_t)NB * 511 * 512 * 2 * 2, stream);
    k_dinv<<<dim3((NB * NI2 + 255) / 256), dim3(256), 0, stream>>>(coef, dinv);
    k_genDSTA<<<dim3((513 * 512 + 255) / 256), dim3(256), 0, stream>>>(sGh, sGl);
    k_genDSTB<<<dim3((513 * 512 + 255) / 256), dim3(256), 0, stream>>>(sGth, sGtl);
    k_genFA<<<dim3((511 * 1056 + 255) / 256), dim3(256), 0, stream>>>(sFAh, sFAl);
    k_genFB<<<dim3((1022 * 1056 + 255) / 256), dim3(256), 0, stream>>>(sFBh, sFBl);
    k_compose<<<dim3(2, NB), dim3(128), 0, stream>>>(w1r, w1i, w2r, w2i, w3r, w3i, kcomp);

    float* xa = x0;
    float* xb = x1;
    for (int step = 0; step < 2; ++step) {
        // 10 weighted-Jacobi sweeps as 2 fused 5-sweep launches
        for (int it = 0; it < 2; ++it) {
            k_jacobi5<<<grdS, blk2, 0, stream>>>(xa, coef, f, dinv, xb);
            float* t = xa; xa = xb; xb = t;
        }
        // residual + fused bf16 transpose planes for gemm1 B
        k_stencil<<<grdS, blk2, 0, stream>>>(xa, coef, f, rr, 0, dB1h, dB1l);

        // ---- H_apply ----
        // gemm1: t2 = G(257x511) * rI(511x511)   [antisym: M 513 -> 257]
        k_mgemm<<<dim3(4, 3, NB * SP), dim3(256), 0, stream>>>(
            sGh, sGl, 0, dB1h, dB1l, (long long)511 * 512,
            pr, (long long)257 * 511, 257, 511, 512, SP);
        k_redA<<<dim3((257 * 512 + 255) / 256, NB), dim3(256), 0, stream>>>(
            pr, SP, 257, dA2h, dA2l);
        // gemm2: rh_q = t2(257x511) * Gt(511x257) [antisym: N 513 -> 257]
        k_mgemm<<<dim3(3, 3, NB * SP), dim3(256), 0, stream>>>(
            dA2h, dA2l, (long long)257 * 512, sGth, sGtl, 0,
            pr, (long long)NQ, 257, 257, 512, SP);
        k_reduce<<<dim3(259, NB), dim3(256), 0, stream>>>(
            pr, rhq, NQ, 257, 257, (long long)NQ, SP);

        // forward conv chain (rh mirror-read) -> or_/oi_
        k_conv7<0><<<grdC, blk2, 0, stream>>>(
            rhq, nullptr, nullptr, nullptr, kcomp, or_, oi_, nullptr, nullptr);
        k_ring7<0><<<grdR, dim3(256), 0, stream>>>(
            rhq, nullptr, nullptr, nullptr,
            w1r, w1i, w2r, w2i, w3r, w3i, or_, oi_, nullptr, nullptr);
        // adjoint conv chain (fused wt*ik2 scale on load) -> bf16 dA3 planes
        k_conv7<1><<<grdC, blk2, 0, stream>>>(
            or_, oi_, wtr, wti, kcomp, nullptr, nullptr, dA3h, dA3l);
        k_ring7<1><<<grdR, dim3(256), 0, stream>>>(
            or_, oi_, wtr, wti,
            w1r, w1i, w2r, w2i, w3r, w3i, nullptr, nullptr, dA3h, dA3l);

        // gemm3' (transposed): P'[n<1022][m<513] = sFB * dA3^T
        k_mgemm<<<dim3(5, 8, NB * 4), dim3(256), 0, stream>>>(
            sFBh, sFBl, 0, dA3h, dA3l, (long long)513 * 1056,
            pr, 1022LL * 513, 1022, 513, 1056, 4);
        k_redBt<<<dim3(2109, NB), dim3(256), 0, stream>>>(pr, 4, dB4h, dB4l);
        // gemm4: e = [Fr|Fi](511x1026) * [t2r;-t2i](1026x511)
        k_mgemm<<<dim3(4, 4, NB * SP), dim3(256), 0, stream>>>(
            sFAh, sFAl, 0, dB4h, dB4l, (long long)511 * 1056,
            pr, (long long)NI2, 511, 511, 1056, SP);
        hipMemsetAsync(ee, 0, (size_t)NB * N2G * sizeof(float), stream);
        k_reduce<<<dim3(1024, NB), dim3(256), 0, stream>>>(
            pr, ee + NGRID + 1, NI2, NINT, NGRID, (long long)N2G, SP);

        // Ae = A e ; alpha = (r.e)/(Ae.e) ; x += alpha e
        k_stencil<<<grdS, blk2, 0, stream>>>(ee, coef, nullptr, Ae, 2,
                                             nullptr, nullptr);
        hipMemsetAsync(red, 0, 8 * sizeof(float), stream);
        k_dot2<<<dim3(64, NB), dim3(256), 0, stream>>>(rr, ee, Ae, red);
        k_update<<<dim3((NB * N2G + 255) / 256), dim3(256), 0, stream>>>(xa, ee, red);
    }
    k_stencil<<<grdS, blk2, 0, stream>>>(xa, coef, f, rr, 0, nullptr, nullptr);
    hipMemsetAsync(red + 8, 0, 2 * sizeof(float), stream);
    k_norm<<<dim3(256), dim3(256), 0, stream>>>(rr, f, red);
    k_final<<<dim3(1), dim3(1), 0, stream>>>(red, out);
}